// Round 13
// baseline (425.612 us; speedup 1.0000x reference)
//
#include <hip/hip_runtime.h>
#include <math.h>

// Problem constants
#define BGRAPH 64
#define NNODE  512
#define NTOT   32768        // BGRAPH*NNODE
#define CIN    128
#define HDIM   128
#define EDIM_  5
#define EDGES  524288
#define EPG    8192         // edges per graph
#define K1C    256
#define K2C    128

using f32x4 = __attribute__((ext_vector_type(4))) float;
using s16x8 = __attribute__((ext_vector_type(8))) short;

__device__ __forceinline__ short f2bf(float f) {
    union { float f; unsigned u; } v; v.f = f;
    unsigned r = v.u + 0x7fffu + ((v.u >> 16) & 1u);   // RNE
    return (short)(r >> 16);
}
__device__ __forceinline__ float bf2f(short s) {
    union { unsigned u; float f; } v; v.u = ((unsigned)(unsigned short)s) << 16;
    return v.f;
}

// ---------------------------------------------------------------------------
// MERGED prep: BatchNorm stats (blocks 0..255) + weight pack (256..511).
// W4 now packed DIRECTLY as bf16 (same f2bf value as the old per-block
// conversion — applied once here instead of redundantly by 1024 GEMM blocks).
// ---------------------------------------------------------------------------
__global__ __launch_bounds__(256) void prep_kernel(const float* __restrict__ x,
                                                   float* __restrict__ psum,
                                                   float* __restrict__ psq,
                                                   const float* __restrict__ Wq, const float* __restrict__ Wk,
                                                   const float* __restrict__ Wv, const float* __restrict__ Ws,
                                                   const float* __restrict__ bq, const float* __restrict__ bk,
                                                   const float* __restrict__ bv, const float* __restrict__ bs,
                                                   short* __restrict__ W4b, float* __restrict__ bias4) {
    __shared__ float ss[128], sq[128];
    int tid = threadIdx.x, bid = blockIdx.x;
    if (bid < 256) {
        long idx0 = (long)bid * 256 + tid;
        float4 s = {0.f, 0.f, 0.f, 0.f}, q = {0.f, 0.f, 0.f, 0.f};
#pragma unroll
        for (int it = 0; it < 16; ++it) {
            float4 v = *(const float4*)(x + (idx0 + (long)it * 65536) * 4);
            s.x += v.x; s.y += v.y; s.z += v.z; s.w += v.w;
            q.x += v.x * v.x; q.y += v.y * v.y; q.z += v.z * v.z; q.w += v.w * v.w;
        }
        if (tid < 128) { ss[tid] = 0.f; sq[tid] = 0.f; }
        __syncthreads();
        int c0 = (tid & 31) * 4;
        atomicAdd(&ss[c0 + 0], s.x); atomicAdd(&ss[c0 + 1], s.y);
        atomicAdd(&ss[c0 + 2], s.z); atomicAdd(&ss[c0 + 3], s.w);
        atomicAdd(&sq[c0 + 0], q.x); atomicAdd(&sq[c0 + 1], q.y);
        atomicAdd(&sq[c0 + 2], q.z); atomicAdd(&sq[c0 + 3], q.w);
        __syncthreads();
        if (tid < 128) {
            psum[bid * 128 + tid] = ss[tid];
            psq[bid * 128 + tid]  = sq[tid];
        }
    } else {
        int i = (bid - 256) * 256 + tid;
        if (i < 128 * 512) {
            int k = i / 512, j = i % 512;
            float v;
            if (j < 128)      v = Wq[k * 128 + j];
            else if (j < 256) v = Wk[k * 128 + (j - 128)];
            else if (j < 384) v = Wv[k * 128 + (j - 256)];
            else              v = Ws[k * 128 + (j - 384)];
            W4b[i] = f2bf(v);
        }
        if (i < 512) {
            float v;
            if (i < 128)      v = bq[i];
            else if (i < 256) v = bk[i - 128];
            else if (i < 384) v = bv[i - 256];
            else              v = bs[i - 384];
            bias4[i] = v;
        }
    }
}

// ---------------------------------------------------------------------------
// BatchNorm finalize + gsum zero (1 block).
// ---------------------------------------------------------------------------
__global__ __launch_bounds__(1024) void fin_kernel(const float* __restrict__ psum,
                                                   const float* __restrict__ psq,
                                                   const float* __restrict__ gamma,
                                                   const float* __restrict__ beta,
                                                   float* __restrict__ scale,
                                                   float* __restrict__ shift,
                                                   float* __restrict__ gsum) {
    int tid = threadIdx.x;
    if (tid < 128) {
        int c = tid;
        float s = 0.f, q = 0.f;
        for (int b = 0; b < 256; ++b) { s += psum[b * 128 + c]; q += psq[b * 128 + c]; }
        float mu  = s / (float)NTOT;
        float var = q / (float)NTOT - mu * mu;
        float rstd = rsqrtf(var + 1e-5f);
        float sc = gamma[c] * rstd;
        scale[c] = sc;
        shift[c] = beta[c] - mu * sc;
    }
    for (int i = tid; i < BGRAPH * 128; i += 1024) gsum[i] = 0.f;
}

// ---------------------------------------------------------------------------
// BF16 MFMA GEMM body (device), tile TILE x TILE (128 or 64), BK=32.
//   AU8: A uint8. ATRBF16: TRANS_A bf16 A. ABF16: !TRANS_A bf16 A.
//   BBF16: B bf16. OBF16: bf16 out. DUAL: concat-K second source.
//   ANORM: A is raw pooled adjacency; apply (r==c?0:v*dinv[r]*dinv[c]) at
//   staging; dvl (LDS) filled from `scale` = rowsum buffer (stride lda).
//   ROWSUM: epilogue accumulates per-row sums of C (diag excluded) into
//   (float*)shift via deterministic shfl reduce + commutative atomics.
// Block coords passed explicitly so merged wrappers can remap blocks.
// ---------------------------------------------------------------------------
template <int TILE, bool TRANS_A, bool AFFINE, bool ANORM, bool ROWSUM, bool RELU,
          bool DUAL, bool OBF16, bool AU8, bool BBF16, bool ATRBF16, bool ABF16>
__device__ __forceinline__ void mgemm_body(short* As, short* Bs, float* dvl,
                                           const void* __restrict__ Av,
                                           const void* __restrict__ Bv,
                                           const void* __restrict__ A2v,
                                           const void* __restrict__ B2v,
                                           int Ksplit,
                                           const float* __restrict__ bias,
                                           void* __restrict__ Cv,
                                           const float* __restrict__ scale,
                                           const float* __restrict__ shift,
                                           int M, int Nc, int K,
                                           int lda, int ldb, int ldc,
                                           long sA, long sB, long sC,
                                           int bx, int by, int bz) {
    constexpr int ASZ = AU8 ? 1 : ((ATRBF16 || ABF16) ? 2 : 4);
    constexpr int BSZ = BBF16 ? 2 : 4;
    const char* Abase = (const char*)Av + (long)bz * sA * ASZ;
    const char* Bbase = (const char*)Bv + (long)bz * sB * BSZ;
    float* C = (float*)Cv + (OBF16 ? 0 : (long)bz * sC);
    short* Cs = (short*)Cv + (OBF16 ? (long)bz * sC : 0);
    const int m0 = by * TILE, n0 = bx * TILE;
    const int tid = threadIdx.x;
    const int lane16 = tid & 15;
    const int quad = (tid & 63) >> 4;
    const int wrow = (tid >> 6) >> 1, wcol = (tid >> 6) & 1;
    constexpr int WT = TILE / 32;

    if (ANORM) {
        for (int i = tid; i < K; i += 256)
            dvl[i] = 1.f / (sqrtf(scale[(long)bz * lda + i]) + 1e-15f);
        __syncthreads();
    }

    f32x4 acc[WT][WT] = {};

    for (int k0 = 0; k0 < K; k0 += 32) {
        const char* Au = Abase; const char* Bu = Bbase; int ku = k0;
        if (DUAL && k0 >= Ksplit) { Au = (const char*)A2v; Bu = (const char*)B2v; ku = k0 - Ksplit; }

        if (!TRANS_A) {
#pragma unroll
            for (int p = 0; p < TILE / 32; ++p) {
                int idx = tid + p * 256;
                int row = idx >> 3, c4 = idx & 7;
                short4 o;
                if (AU8) {
                    unsigned u = *(const unsigned*)((const unsigned char*)Au +
                                                    (long)(m0 + row) * lda + ku + c4 * 4);
                    o = make_short4(f2bf((float)(u & 255u)), f2bf((float)((u >> 8) & 255u)),
                                    f2bf((float)((u >> 16) & 255u)), f2bf((float)((u >> 24) & 255u)));
                } else if (ABF16) {
                    o = *(const short4*)((const short*)Au + (long)(m0 + row) * lda + ku + c4 * 4);
                } else {
                    float4 v = *(const float4*)((const float*)Au + (long)(m0 + row) * lda + ku + c4 * 4);
                    if (AFFINE) {
                        int k = ku + c4 * 4;
                        v.x = v.x * scale[k] + shift[k];
                        v.y = v.y * scale[k + 1] + shift[k + 1];
                        v.z = v.z * scale[k + 2] + shift[k + 2];
                        v.w = v.w * scale[k + 3] + shift[k + 3];
                    }
                    if (ANORM) {
                        int k = ku + c4 * 4;
                        int grow = m0 + row;
                        float dr = dvl[grow];
                        v.x = (grow == k + 0) ? 0.f : v.x * dr * dvl[k + 0];
                        v.y = (grow == k + 1) ? 0.f : v.y * dr * dvl[k + 1];
                        v.z = (grow == k + 2) ? 0.f : v.z * dr * dvl[k + 2];
                        v.w = (grow == k + 3) ? 0.f : v.w * dr * dvl[k + 3];
                    }
                    o = make_short4(f2bf(v.x), f2bf(v.y), f2bf(v.z), f2bf(v.w));
                }
                *(short4*)&As[row * 40 + c4 * 4] = o;
            }
        } else {
            if (TILE == 128 || tid < 128) {
                int c4 = tid >> 3, g = tid & 7;        // row-group slow, k-group fast
                short* d = &As[(c4 * 4) * 40 + g * 4];
                if (ATRBF16) {
                    const short* src = (const short*)Au + (long)(ku + g * 4) * lda + m0 + c4 * 4;
                    short4 r0 = *(const short4*)(src);
                    short4 r1 = *(const short4*)(src + lda);
                    short4 r2 = *(const short4*)(src + 2 * lda);
                    short4 r3 = *(const short4*)(src + 3 * lda);
                    *(short4*)(d + 0 * 40) = make_short4(r0.x, r1.x, r2.x, r3.x);
                    *(short4*)(d + 1 * 40) = make_short4(r0.y, r1.y, r2.y, r3.y);
                    *(short4*)(d + 2 * 40) = make_short4(r0.z, r1.z, r2.z, r3.z);
                    *(short4*)(d + 3 * 40) = make_short4(r0.w, r1.w, r2.w, r3.w);
                } else {
                    const float* src = (const float*)Au + (long)(ku + g * 4) * lda + m0 + c4 * 4;
                    float4 r0 = *(const float4*)(src);
                    float4 r1 = *(const float4*)(src + lda);
                    float4 r2 = *(const float4*)(src + 2 * lda);
                    float4 r3 = *(const float4*)(src + 3 * lda);
                    *(short4*)(d + 0 * 40) = make_short4(f2bf(r0.x), f2bf(r1.x), f2bf(r2.x), f2bf(r3.x));
                    *(short4*)(d + 1 * 40) = make_short4(f2bf(r0.y), f2bf(r1.y), f2bf(r2.y), f2bf(r3.y));
                    *(short4*)(d + 2 * 40) = make_short4(f2bf(r0.z), f2bf(r1.z), f2bf(r2.z), f2bf(r3.z));
                    *(short4*)(d + 3 * 40) = make_short4(f2bf(r0.w), f2bf(r1.w), f2bf(r2.w), f2bf(r3.w));
                }
            }
        }
        if (TILE == 128 || tid < 128) {
            int c4 = tid >> 3, g = tid & 7;            // n-group slow, k-group fast
            short* d = &Bs[(c4 * 4) * 40 + g * 4];
            if (BBF16) {
                const short* src = (const short*)Bu + (long)(ku + g * 4) * ldb + n0 + c4 * 4;
                short4 r0 = *(const short4*)(src);
                short4 r1 = *(const short4*)(src + ldb);
                short4 r2 = *(const short4*)(src + 2 * ldb);
                short4 r3 = *(const short4*)(src + 3 * ldb);
                *(short4*)(d + 0 * 40) = make_short4(r0.x, r1.x, r2.x, r3.x);
                *(short4*)(d + 1 * 40) = make_short4(r0.y, r1.y, r2.y, r3.y);
                *(short4*)(d + 2 * 40) = make_short4(r0.z, r1.z, r2.z, r3.z);
                *(short4*)(d + 3 * 40) = make_short4(r0.w, r1.w, r2.w, r3.w);
            } else {
                const float* src = (const float*)Bu + (long)(ku + g * 4) * ldb + n0 + c4 * 4;
                float4 r0 = *(const float4*)(src);
                float4 r1 = *(const float4*)(src + ldb);
                float4 r2 = *(const float4*)(src + 2 * ldb);
                float4 r3 = *(const float4*)(src + 3 * ldb);
                *(short4*)(d + 0 * 40) = make_short4(f2bf(r0.x), f2bf(r1.x), f2bf(r2.x), f2bf(r3.x));
                *(short4*)(d + 1 * 40) = make_short4(f2bf(r0.y), f2bf(r1.y), f2bf(r2.y), f2bf(r3.y));
                *(short4*)(d + 2 * 40) = make_short4(f2bf(r0.z), f2bf(r1.z), f2bf(r2.z), f2bf(r3.z));
                *(short4*)(d + 3 * 40) = make_short4(f2bf(r0.w), f2bf(r1.w), f2bf(r2.w), f2bf(r3.w));
            }
        }
        __syncthreads();

        s16x8 af[WT], bf[WT];
#pragma unroll
        for (int t = 0; t < WT; ++t) {
            af[t] = *(const s16x8*)&As[(wrow * (TILE / 2) + t * 16 + lane16) * 40 + quad * 8];
            bf[t] = *(const s16x8*)&Bs[(wcol * (TILE / 2) + t * 16 + lane16) * 40 + quad * 8];
        }
#pragma unroll
        for (int i = 0; i < WT; ++i)
#pragma unroll
            for (int j = 0; j < WT; ++j)
                acc[i][j] = __builtin_amdgcn_mfma_f32_16x16x32_bf16(af[i], bf[j], acc[i][j], 0, 0, 0);
        __syncthreads();
    }

#pragma unroll
    for (int i = 0; i < WT; ++i) {
        int gm = m0 + wrow * (TILE / 2) + i * 16 + quad * 4;
#pragma unroll
        for (int j = 0; j < WT; ++j) {
            int gn = n0 + wcol * (TILE / 2) + j * 16 + lane16;
            float bv = bias ? bias[gn] : 0.f;
#pragma unroll
            for (int r = 0; r < 4; ++r) {
                float val = acc[i][j][r] + bv;
                if (RELU) val = fmaxf(val, 0.f);
                if (OBF16) Cs[(long)(gm + r) * ldc + gn] = f2bf(val);
                else       C[(long)(gm + r) * ldc + gn] = val;
            }
        }
    }

    if (ROWSUM) {
        float* rlA = (float*)As;
        float* rlB = (float*)Bs;
#pragma unroll
        for (int i = 0; i < WT; ++i) {
#pragma unroll
            for (int r = 0; r < 4; ++r) {
                int gm = m0 + wrow * (TILE / 2) + i * 16 + quad * 4 + r;
                float p = 0.f;
#pragma unroll
                for (int j = 0; j < WT; ++j) {
                    int gn = n0 + wcol * (TILE / 2) + j * 16 + lane16;
                    p += (gn == gm) ? 0.f : acc[i][j][r];
                }
#pragma unroll
                for (int off = 1; off < 16; off <<= 1) p += __shfl_xor(p, off);
                if (lane16 == 0) {
                    int rl = wrow * (TILE / 2) + i * 16 + quad * 4 + r;
                    (wcol ? rlB : rlA)[rl] = p;
                }
            }
        }
        __syncthreads();
        float* rout = (float*)shift;
        for (int t = tid; t < TILE; t += 256)
            atomicAdd(&rout[(long)bz * M + m0 + t], rlA[t] + rlB[t]);
    }
}

// Standalone wrapper (used for adj2)
template <int TILE, bool TRANS_A, bool AFFINE, bool ANORM, bool ROWSUM, bool RELU,
          bool DUAL, bool OBF16, bool AU8, bool BBF16, bool ATRBF16, bool ABF16>
__global__ __launch_bounds__(256) void mgemm(const void* __restrict__ Av,
                                             const void* __restrict__ Bv,
                                             const void* __restrict__ A2v,
                                             const void* __restrict__ B2v,
                                             int Ksplit,
                                             const float* __restrict__ bias,
                                             void* __restrict__ Cv,
                                             const float* __restrict__ scale,
                                             const float* __restrict__ shift,
                                             int M, int Nc, int K,
                                             int lda, int ldb, int ldc,
                                             long sA, long sB, long sC) {
    __shared__ __align__(16) short As[TILE * 40];
    __shared__ __align__(16) short Bs[TILE * 40];
    __shared__ float dvl[ANORM ? 256 : 1];
    mgemm_body<TILE, TRANS_A, AFFINE, ANORM, ROWSUM, RELU, DUAL, OBF16, AU8, BBF16, ATRBF16, ABF16>(
        As, Bs, dvl, Av, Bv, A2v, B2v, Ksplit, bias, Cv, scale, shift,
        M, Nc, K, lda, ldb, ldc, sA, sB, sC,
        blockIdx.x, blockIdx.y, blockIdx.z);
}

// ---------------------------------------------------------------------------
// Per-graph LDS CSR build (one block per graph+direction): histogram via LDS
// atomics, 512-entry LDS scan, then scatter eid DIRECTLY to global (positions
// from LDS cursors — no global atomics; each graph's 32KB eid span is written
// by a single block so lines stay L2-private, one writeback).
// smemInt layout: cnt[512] | part[256]  (3072 B)
// ---------------------------------------------------------------------------
__device__ __forceinline__ void csr_build_graph(int* smemInt,
                                                const int* __restrict__ ei_dir,
                                                int gnode0, int gedge0,
                                                int* __restrict__ rp,
                                                int* __restrict__ deg,
                                                int* __restrict__ eid) {
    int* cnt  = smemInt;
    int* part = smemInt + 512;
    int tid = threadIdx.x;
    cnt[tid] = 0; cnt[tid + 256] = 0;
    __syncthreads();
    // histogram
    for (int k = 0; k < EPG / 256; ++k) {
        int e = gedge0 + k * 256 + tid;
        atomicAdd(&cnt[ei_dir[e] & 511], 1);
    }
    __syncthreads();
    // exclusive scan over 512 (thread t owns counters 2t, 2t+1)
    int c0 = cnt[2 * tid], c1 = cnt[2 * tid + 1];
    part[tid] = c0 + c1;
    __syncthreads();
    for (int off = 1; off < 256; off <<= 1) {
        int v = part[tid];
        int add = (tid >= off) ? part[tid - off] : 0;
        __syncthreads();
        part[tid] = v + add;
        __syncthreads();
    }
    int excl = (tid == 0) ? 0 : part[tid - 1];
    rp[gnode0 + 2 * tid]      = gedge0 + excl;
    rp[gnode0 + 2 * tid + 1]  = gedge0 + excl + c0;
    deg[gnode0 + 2 * tid]     = c0;
    deg[gnode0 + 2 * tid + 1] = c1;
    cnt[2 * tid]     = excl;        // becomes local cursor
    cnt[2 * tid + 1] = excl + c0;
    __syncthreads();
    // scatter directly to global (span is block-private -> L2-local)
    for (int k = 0; k < EPG / 256; ++k) {
        int e = gedge0 + k * 256 + tid;
        int pos = atomicAdd(&cnt[ei_dir[e] & 511], 1);
        eid[gedge0 + pos] = e;
    }
}

// ---------------------------------------------------------------------------
// MERGED: qkvs GEMM (blocks 0..1023, B = pre-packed bf16 W4b -> cheap BBF16
// staging) + per-graph LDS CSR build (1024..1151). LDS = 20480 B.
// ---------------------------------------------------------------------------
__global__ __launch_bounds__(256) void qkvs_csr_kernel(const float* __restrict__ x,
                                                       const short* __restrict__ W4b,
                                                       const float* __restrict__ bias4,
                                                       short* __restrict__ qkvs,
                                                       const float* __restrict__ scale,
                                                       const float* __restrict__ shift,
                                                       const int* __restrict__ ei,
                                                       int* __restrict__ rp_src,
                                                       int* __restrict__ deg_src,
                                                       int* __restrict__ eid_src,
                                                       int* __restrict__ rp_dst,
                                                       int* __restrict__ deg_dst,
                                                       int* __restrict__ eid_dst) {
    __shared__ __align__(16) char smem[20480];
    int b = blockIdx.x;
    if (b < 1024) {
        short* As = (short*)smem;
        short* Bs = (short*)(smem + 10240);
        mgemm_body<128, false, true, false, false, false, false, true, false, true, false, false>(
            As, Bs, nullptr, x, W4b, nullptr, nullptr, 0, bias4, qkvs, scale, shift,
            NTOT, 512, 128, 128, 512, 512, 0, 0, 0,
            b & 3, b >> 2, 0);
    } else {
        int j = b - 1024;                    // [0,128): graph = j>>1, dir = j&1
        int g = j >> 1;
        if (j & 1)
            csr_build_graph((int*)smem, ei + EDGES, g * NNODE, g * EPG,
                            rp_dst, deg_dst, eid_dst);
        else
            csr_build_graph((int*)smem, ei, g * NNODE, g * EPG,
                            rp_src, deg_src, eid_src);
    }
}

// ---------------------------------------------------------------------------
// MERGED pool1: xp1 = s1b^T h (blocks 0..511) ∥ adj1(raw)=s1b^T T1s + ROWSUM
// (blocks 512..767). Outputs disjoint (h at 112MB; adj1 at 80MB).
// ---------------------------------------------------------------------------
__global__ __launch_bounds__(256) void pool1_kernel(const short* __restrict__ s1b,
                                                    const short* __restrict__ h,
                                                    const short* __restrict__ T1s,
                                                    float* __restrict__ xp1,
                                                    float* __restrict__ adj1,
                                                    float* __restrict__ rowsum1) {
    __shared__ __align__(16) short As[128 * 40];
    __shared__ __align__(16) short Bs[128 * 40];
    int b = blockIdx.x;
    if (b < 512) {
        mgemm_body<64, true, false, false, false, false, false, false, false, true, true, false>(
            As, Bs, nullptr, s1b, h, nullptr, nullptr, 0, nullptr, xp1, nullptr, nullptr,
            K1C, 128, NNODE, K1C, 128, 128,
            (long)NNODE * K1C, (long)NNODE * 128, (long)K1C * 128,
            b & 1, (b >> 1) & 3, b >> 3);
    } else {
        int j = b - 512;
        mgemm_body<128, true, false, false, true, false, false, false, false, true, true, false>(
            As, Bs, nullptr, s1b, T1s, nullptr, nullptr, 0, nullptr, adj1, nullptr, rowsum1,
            K1C, K1C, NNODE, K1C, K1C, K1C,
            (long)NNODE * K1C, (long)NNODE * K1C, (long)K1C * K1C,
            j & 1, (j >> 1) & 1, j >> 2);
    }
}

// ---------------------------------------------------------------------------
// MERGED pool2: t2 = adjN1@s2b (ANORM, blocks 0..511) ∥ xp2 = s2b^T xd2
// (blocks 512..767). Outputs disjoint (t2@64MB, xp2@4MB).
// ---------------------------------------------------------------------------
__global__ __launch_bounds__(256) void pool2_kernel(const float* __restrict__ adj1,
                                                    const float* __restrict__ rowsum1,
                                                    const short* __restrict__ s2b,
                                                    const short* __restrict__ xd2,
                                                    float* __restrict__ t2,
                                                    float* __restrict__ xp2) {
    __shared__ __align__(16) short As[64 * 40];
    __shared__ __align__(16) short Bs[64 * 40];
    __shared__ float dvl[256];
    int b = blockIdx.x;
    if (b < 512) {
        mgemm_body<64, false, false, true, false, false, false, false, false, true, false, false>(
            As, Bs, dvl, adj1, s2b, nullptr, nullptr, 0, nullptr, t2, rowsum1, nullptr,
            K1C, K2C, K1C, K1C, K2C, K2C,
            (long)K1C * K1C, (long)K1C * K2C, (long)K1C * K2C,
            b & 1, (b >> 1) & 3, b >> 3);
    } else {
        int j = b - 512;
        mgemm_body<64, true, false, false, false, false, false, false, false, true, true, false>(
            As, Bs, nullptr, s2b, xd2, nullptr, nullptr, 0, nullptr, xp2, nullptr, nullptr,
            K2C, 128, K1C, K2C, 128, 128,
            (long)K1C * K2C, (long)K1C * 128, (long)K2C * 128,
            j & 1, (j >> 1) & 1, j >> 2);
    }
}

// ---------------------------------------------------------------------------
// FUSED DenseGraphConv: Out = act( adjN@xp @ Wrel + xp @ Wroot + b )
// adjN normalized on the fly from raw adj + rowsum (dinv staged in LDS).
// COLSUM: instead of storing Out, accumulate per-graph column sums (bias
// included) into (float*)Outv = gsum[B][128] — feeds the readout mean.
// ---------------------------------------------------------------------------
template <int KADJ, bool RELU, bool OBF16, bool COLSUM>
__global__ __launch_bounds__(256) void fused_gc_kernel(const float* __restrict__ adj,
                                                       const float* __restrict__ rowsum,
                                                       const float* __restrict__ xp,
                                                       const float* __restrict__ Wrel,
                                                       const float* __restrict__ brel,
                                                       const float* __restrict__ Wroot,
                                                       void* __restrict__ Outv) {
    __shared__ __align__(16) short As[64 * 40];
    __shared__ __align__(16) short Bs[128 * 40];
    __shared__ __align__(16) short Tl[64][136];
    __shared__ float dvl[KADJ];
    __shared__ float cs[COLSUM ? 128 : 1];
    const int z = blockIdx.y;
    const int m0 = blockIdx.x * 64;
    const int tid = threadIdx.x;
    const int lane16 = tid & 15;
    const int quad = (tid & 63) >> 4;
    const int wrow = (tid >> 6) >> 1, wcol = (tid >> 6) & 1;
    const float* adjz = adj + (long)z * KADJ * KADJ;
    const float* xpz  = xp + (long)z * KADJ * 128;

    for (int i = tid; i < KADJ; i += 256)
        dvl[i] = 1.f / (sqrtf(rowsum[(long)z * KADJ + i]) + 1e-15f);
    if (COLSUM) for (int i = tid; i < 128; i += 256) cs[i] = 0.f;
    __syncthreads();

    // ---- phase 1: T[64][128] = adjN[m0..m0+64) @ xp ----
    f32x4 acc[2][4] = {};
    for (int k0 = 0; k0 < KADJ; k0 += 32) {
#pragma unroll
        for (int p = 0; p < 2; ++p) {
            int idx = tid + p * 256;
            int row = idx >> 3, c4 = idx & 7;
            int grow = m0 + row, k = k0 + c4 * 4;
            float4 v = *(const float4*)(adjz + (long)grow * KADJ + k);
            float dr = dvl[grow];
            v.x = (grow == k + 0) ? 0.f : v.x * dr * dvl[k + 0];
            v.y = (grow == k + 1) ? 0.f : v.y * dr * dvl[k + 1];
            v.z = (grow == k + 2) ? 0.f : v.z * dr * dvl[k + 2];
            v.w = (grow == k + 3) ? 0.f : v.w * dr * dvl[k + 3];
            *(short4*)&As[row * 40 + c4 * 4] =
                make_short4(f2bf(v.x), f2bf(v.y), f2bf(v.z), f2bf(v.w));
        }
        {
            int c4 = tid >> 3, g = tid & 7;
            short* d = &Bs[(c4 * 4) * 40 + g * 4];
            const float* src = xpz + (long)(k0 + g * 4) * 128 + c4 * 4;
            float4 r0 = *(const float4*)(src);
            float4 r1 = *(const float4*)(src + 128);
            float4 r2 = *(const float4*)(src + 256);
            float4 r3 = *(const float4*)(src + 384);
            *(short4*)(d + 0 * 40) = make_short4(f2bf(r0.x), f2bf(r1.x), f2bf(r2.x), f2bf(r3.x));
            *(short4*)(d + 1 * 40) = make_short4(f2bf(r0.y), f2bf(r1.y), f2bf(r2.y), f2bf(r3.y));
            *(short4*)(d + 2 * 40) = make_short4(f2bf(r0.z), f2bf(r1.z), f2bf(r2.z), f2bf(r3.z));
            *(short4*)(d + 3 * 40) = make_short4(f2bf(r0.w), f2bf(r1.w), f2bf(r2.w), f2bf(r3.w));
        }
        __syncthreads();
        s16x8 af[2], bf[4];
#pragma unroll
        for (int t = 0; t < 2; ++t)
            af[t] = *(const s16x8*)&As[(wrow * 32 + t * 16 + lane16) * 40 + quad * 8];
#pragma unroll
        for (int j = 0; j < 4; ++j)
            bf[j] = *(const s16x8*)&Bs[(wcol * 64 + j * 16 + lane16) * 40 + quad * 8];
#pragma unroll
        for (int t = 0; t < 2; ++t)
#pragma unroll
            for (int j = 0; j < 4; ++j)
                acc[t][j] = __builtin_amdgcn_mfma_f32_16x16x32_bf16(af[t], bf[j], acc[t][j], 0, 0, 0);
        __syncthreads();
    }
#pragma unroll
    for (int t = 0; t < 2; ++t)
#pragma unroll
        for (int j = 0; j < 4; ++j)
#pragma unroll
            for (int r = 0; r < 4; ++r)
                Tl[wrow * 32 + t * 16 + quad * 4 + r][wcol * 64 + j * 16 + lane16] =
                    f2bf(acc[t][j][r]);
    __syncthreads();

    // ---- phase 2: Out = [T | xp_rows] @ [Wrel; Wroot] + b ----
    f32x4 acc2[2][4] = {};
    for (int k0 = 0; k0 < 256; k0 += 32) {
        const bool useXp = (k0 >= 128);
        const float* Wsrc = useXp ? (Wroot + (long)(k0 - 128) * 128)
                                  : (Wrel + (long)k0 * 128);
        {
            int c4 = tid >> 3, g = tid & 7;
            short* d = &Bs[(c4 * 4) * 40 + g * 4];
            const float* src = Wsrc + (long)(g * 4) * 128 + c4 * 4;
            float4 r0 = *(const float4*)(src);
            float4 r1 = *(const float4*)(src + 128);
            float4 r2 = *(const float4*)(src + 256);
            float4 r3 = *(const float4*)(src + 384);
            *(short4*)(d + 0 * 40) = make_short4(f2bf(r0.x), f2bf(r1.x), f2bf(r2.x), f2bf(r3.x));
            *(short4*)(d + 1 * 40) = make_short4(f2bf(r0.y), f2bf(r1.y), f2bf(r2.y), f2bf(r3.y));
            *(short4*)(d + 2 * 40) = make_short4(f2bf(r0.z), f2bf(r1.z), f2bf(r2.z), f2bf(r3.z));
            *(short4*)(d + 3 * 40) = make_short4(f2bf(r0.w), f2bf(r1.w), f2bf(r2.w), f2bf(r3.w));
        }
        if (useXp) {
#pragma unroll
            for (int p = 0; p < 2; ++p) {
                int idx = tid + p * 256;
                int row = idx >> 3, c4 = idx & 7;
                float4 v = *(const float4*)(xpz + (long)(m0 + row) * 128 + (k0 - 128) + c4 * 4);
                *(short4*)&As[row * 40 + c4 * 4] =
                    make_short4(f2bf(v.x), f2bf(v.y), f2bf(v.z), f2bf(v.w));
            }
        }
        __syncthreads();
        s16x8 af[2], bf[4];
#pragma unroll
        for (int t = 0; t < 2; ++t) {
            int ar = wrow * 32 + t * 16 + lane16;
            af[t] = useXp ? *(const s16x8*)&As[ar * 40 + quad * 8]
                          : *(const s16x8*)&Tl[ar][k0 + quad * 8];
        }
#pragma unroll
        for (int j = 0; j < 4; ++j)
            bf[j] = *(const s16x8*)&Bs[(wcol * 64 + j * 16 + lane16) * 40 + quad * 8];
#pragma unroll
        for (int t = 0; t < 2; ++t)
#pragma unroll
            for (int j = 0; j < 4; ++j)
                acc2[t][j] = __builtin_amdgcn_mfma_f32_16x16x32_bf16(af[t], bf[j], acc2[t][j], 0, 0, 0);
        __syncthreads();
    }

    if (!COLSUM) {
        float* Of = (float*)Outv;
        short* Ob = (short*)Outv;
#pragma unroll
        for (int t = 0; t < 2; ++t) {
#pragma unroll
            for (int j = 0; j < 4; ++j) {
                int gcol = wcol * 64 + j * 16 + lane16;
                float bv = brel[gcol];
#pragma unroll
                for (int r = 0; r < 4; ++r) {
                    int grow = m0 + wrow * 32 + t * 16 + quad * 4 + r;
                    float val = acc2[t][j][r] + bv;
                    if (RELU) val = fmaxf(val, 0.f);
                    long oi = ((long)z * KADJ + grow) * 128 + gcol;
                    if (OBF16) Ob[oi] = f2bf(val);
                    else       Of[oi] = val;
                }
            }
        }
    } else {
#pragma unroll
        for (int j = 0; j < 4; ++j) {
            int gcol = wcol * 64 + j * 16 + lane16;
            float bv = brel[gcol];
            float p = 0.f;
#pragma unroll
            for (int t = 0; t < 2; ++t)
#pragma unroll
                for (int r = 0; r < 4; ++r) {
                    float val = acc2[t][j][r] + bv;
                    if (RELU) val = fmaxf(val, 0.f);
                    p += val;
                }
            atomicAdd(&cs[gcol], p);
        }
        __syncthreads();
        float* gsum = (float*)Outv;
        for (int i = tid; i < 128; i += 256)
            atomicAdd(&gsum[(long)z * 128 + i], cs[i]);
    }
}

// ---------------------------------------------------------------------------
// FUSED MLP + row-softmax: Out = softmax_row(A @ W + b), A bf16 [M,128],
// W f32 [128,NC], Out bf16 [M,NC]. TILE_M=64 (4 waves x 16 rows).
// ---------------------------------------------------------------------------
template <int NC>
__global__ __launch_bounds__(256) void mlp_softmax_kernel(const short* __restrict__ A,
                                                          const float* __restrict__ W,
                                                          const float* __restrict__ bias,
                                                          short* __restrict__ Out) {
    __shared__ __align__(16) short As[64 * 40];
    __shared__ __align__(16) short Ws[NC * 40];
    const int tid = threadIdx.x;
    const int lane16 = tid & 15;
    const int quad = (tid & 63) >> 4;
    const int wv = tid >> 6;
    const int m0 = blockIdx.x * 64;
    constexpr int NT = NC / 16;

    f32x4 acc[NT] = {};

    for (int k0 = 0; k0 < 128; k0 += 32) {
        {
            int row = tid >> 2, g = tid & 3;
            *(s16x8*)&As[row * 40 + g * 8] =
                *(const s16x8*)(A + (long)(m0 + row) * 128 + k0 + g * 8);
        }
#pragma unroll
        for (int p = 0; p < NC / 128; ++p) {
            int c4 = tid >> 3, g = tid & 7;
            int n0 = p * 128 + c4 * 4;
            short* d = &Ws[n0 * 40 + g * 4];
            const float* src = W + (long)(k0 + g * 4) * NC + n0;
            float4 r0 = *(const float4*)(src);
            float4 r1 = *(const float4*)(src + NC);
            float4 r2 = *(const float4*)(src + 2 * NC);
            float4 r3 = *(const float4*)(src + 3 * NC);
            *(short4*)(d + 0 * 40) = make_short4(f2bf(r0.x), f2bf(r1.x), f2bf(r2.x), f2bf(r3.x));
            *(short4*)(d + 1 * 40) = make_short4(f2bf(r0.y), f2bf(r1.y), f2bf(r2.y), f2bf(r3.y));
            *(short4*)(d + 2 * 40) = make_short4(f2bf(r0.z), f2bf(r1.z), f2bf(r2.z), f2bf(r3.z));
            *(short4*)(d + 3 * 40) = make_short4(f2bf(r0.w), f2bf(r1.w), f2bf(r2.w), f2bf(r3.w));
        }
        __syncthreads();

        s16x8 af = *(const s16x8*)&As[(wv * 16 + lane16) * 40 + quad * 8];
#pragma unroll
        for (int t = 0; t < NT; ++t) {
            s16x8 bf = *(const s16x8*)&Ws[(t * 16 + lane16) * 40 + quad * 8];
            acc[t] = __builtin_amdgcn_mfma_f32_16x16x32_bf16(af, bf, acc[t], 0, 0, 0);
        }
        __syncthreads();
    }

    float mx[4] = {-INFINITY, -INFINITY, -INFINITY, -INFINITY};
#pragma unroll
    for (int t = 0; t < NT; ++t) {
        float bv = bias[t * 16 + lane16];
#pragma unroll
        for (int r = 0; r < 4; ++r) {
            float x = bf2f(f2bf(acc[t][r] + bv));
            acc[t][r] = x;
            mx[r] = fmaxf(mx[r], x);
        }
    }
#pragma unroll
    for (int off = 8; off; off >>= 1)
#pragma unroll
        for (int r = 0; r < 4; ++r) mx[r] = fmaxf(mx[r], __shfl_xor(mx[r], off));
    float sm[4] = {0.f, 0.f, 0.f, 0.f};
#pragma unroll
    for (int t = 0; t < NT; ++t)
#pragma unroll
        for (int r = 0; r < 4; ++r) {
            float e = expf(acc[t][r] - mx[r]);
            acc[t][r] = e;
            sm[r] += e;
        }
#pragma unroll
    for (int off = 8; off; off >>= 1)
#pragma unroll
        for (int r = 0; r < 4; ++r) sm[r] += __shfl_xor(sm[r], off);
#pragma unroll
    for (int r = 0; r < 4; ++r) sm[r] = 1.f / sm[r];
#pragma unroll
    for (int t = 0; t < NT; ++t)
#pragma unroll
        for (int r = 0; r < 4; ++r)
            Out[(long)(m0 + wv * 16 + quad * 4 + r) * NC + t * 16 + lane16] =
                f2bf(acc[t][r] * sm[r]);
}

// ---------------------------------------------------------------------------
// BF16-input MFMA GEMM (TRANS_B — used for QK^T): C = scale*(A@B^T).
// Block remap: graph z runs on XCD z>>3 (matching attn_pv's consumer swizzle).
// ---------------------------------------------------------------------------
template <bool OBF16>
__global__ __launch_bounds__(256) void bgemm(const short* __restrict__ A,
                                             const short* __restrict__ B,
                                             void* __restrict__ Cv,
                                             float outscale,
                                             int M, int Nc, int K,
                                             int lda, int ldb, int ldc,
                                             long sA, long sB, long sC) {
    __shared__ __align__(16) short As[128 * 40];
    __shared__ __align__(16) short Bs[128 * 40];
    int L = blockIdx.x + (blockIdx.y << 2) + (blockIdx.z << 4);
    int xcd = L & 7, i = L >> 3;
    const int z = xcd * 8 + (i >> 4);
    const int m0 = ((i >> 2) & 3) * 128, n0 = (i & 3) * 128;
    A += (long)z * sA;
    B += (long)z * sB;
    float* C = (float*)Cv + (OBF16 ? 0 : (long)z * sC);
    short* Cs = (short*)Cv + (OBF16 ? (long)z * sC : 0);
    const int tid = threadIdx.x;
    const int lane16 = tid & 15;
    const int quad = (tid & 63) >> 4;
    const int wrow = (tid >> 6) >> 1, wcol = (tid >> 6) & 1;

    f32x4 acc[4][4] = {};

    for (int k0 = 0; k0 < K; k0 += 32) {
#pragma unroll
        for (int p = 0; p < 2; ++p) {
            int u = tid + p * 256;
            int row = u >> 2, g = u & 3;
            *(s16x8*)&As[row * 40 + g * 8] =
                *(const s16x8*)(A + (long)(m0 + row) * lda + k0 + g * 8);
        }
#pragma unroll
        for (int p = 0; p < 2; ++p) {
            int u = tid + p * 256;
            int row = u >> 2, g = u & 3;
            *(s16x8*)&Bs[row * 40 + g * 8] =
                *(const s16x8*)(B + (long)(n0 + row) * ldb + k0 + g * 8);
        }
        __syncthreads();

        s16x8 af[4], bf[4];
#pragma unroll
        for (int t = 0; t < 4; ++t) {
            af[t] = *(const s16x8*)&As[(wrow * 64 + t * 16 + lane16) * 40 + quad * 8];
            bf[t] = *(const s16x8*)&Bs[(wcol * 64 + t * 16 + lane16) * 40 + quad * 8];
        }
#pragma unroll
        for (int i2 = 0; i2 < 4; ++i2)
#pragma unroll
            for (int j = 0; j < 4; ++j)
                acc[i2][j] = __builtin_amdgcn_mfma_f32_16x16x32_bf16(af[i2], bf[j], acc[i2][j], 0, 0, 0);
        __syncthreads();
    }

#pragma unroll
    for (int i2 = 0; i2 < 4; ++i2) {
        int gm = m0 + wrow * 64 + i2 * 16 + quad * 4;
#pragma unroll
        for (int j = 0; j < 4; ++j) {
            int gn = n0 + wcol * 64 + j * 16 + lane16;
#pragma unroll
            for (int r = 0; r < 4; ++r) {
                float val = acc[i2][j][r] * outscale;
                if (OBF16) Cs[(long)(gm + r) * ldc + gn] = f2bf(val);
                else       C[(long)(gm + r) * ldc + gn] = val;
            }
        }
    }
}

// ---------------------------------------------------------------------------
// FUSED edge-softmax + PV gather. 16 lanes/dst node, XCD-swizzled blocks.
// S-row staged in LDS (round-3 structure — local optimum).
// ---------------------------------------------------------------------------
__global__ __launch_bounds__(256) void attn_pv_kernel(const short* __restrict__ S,
                                                      const int* __restrict__ ei,
                                                      const float* __restrict__ eattr,
                                                      const float* __restrict__ We,
                                                      const int* __restrict__ rp_dst,
                                                      const int* __restrict__ deg_dst,
                                                      const int* __restrict__ eid_dst,
                                                      const short* __restrict__ qkvs,
                                                      float* __restrict__ alpha,
                                                      short* __restrict__ h) {
    __shared__ float sWe[EDIM_ * 128];
    __shared__ __align__(16) short sS[16][528];   // 1KB S-row per group (+pad)
    int g = threadIdx.x >> 4;
    int lane = threadIdx.x & 15;
    int gbase = (threadIdx.x & 63) & ~15;
    int b = blockIdx.x;
    int xcd = b & 7, idx = b >> 3;
    int nb = (xcd * 8 + (idx >> 5)) * 32 + (idx & 31);
    int node = nb * 16 + g;

    {
        const short* Srow = S + (long)node * 512;
        short* Sl = sS[g];
#pragma unroll
        for (int j = 0; j < 4; ++j)
            *(s16x8*)&Sl[j * 128 + lane * 8] = *(const s16x8*)(Srow + j * 128 + lane * 8);
    }
    for (int i = threadIdx.x; i < EDIM_ * 128; i += 256) sWe[i] = We[i];
    __syncthreads();
    const short* Sl = sS[g];

    float qw[EDIM_];
    {
        s16x8 qv = *(const s16x8*)(qkvs + (long)node * 512 + lane * 8);
        float qf[8];
#pragma unroll
        for (int j = 0; j < 8; ++j) qf[j] = bf2f(qv[j]);
#pragma unroll
        for (int d = 0; d < EDIM_; ++d) {
            float p = 0.f;
#pragma unroll
            for (int j = 0; j < 8; ++j) p += qf[j] * sWe[d * 128 + lane * 8 + j];
            qw[d] = p;
        }
#pragma unroll
        for (int off = 8; off; off >>= 1)
#pragma unroll
            for (int d = 0; d < EDIM_; ++d) qw[d] += __shfl_xor(qw[d], off);
#pragma unroll
        for (int d = 0; d < EDIM_; ++d) qw[d] *= 0.08838834764831845f;
    }

    int start = rp_dst[node], cnt = deg_dst[node];
    int nch = (cnt + 15) >> 4;

    float lsum = 0.f, a5[EDIM_] = {};
    int   src_c[4] = {0, 0, 0, 0};
    float a_c[4]   = {0.f, 0.f, 0.f, 0.f};
    for (int c = 0; c < nch; ++c) {
        int t = c * 16 + lane;
        int src = 0; float wv = 0.f;
        if (t < cnt) {
            int e = eid_dst[start + t];
            src = ei[e];
            float lg = bf2f(Sl[src & 511]);
            float ea[EDIM_];
#pragma unroll
            for (int d = 0; d < EDIM_; ++d) { ea[d] = eattr[e * EDIM_ + d]; lg += ea[d] * qw[d]; }
            wv = expf(lg);
            lsum += wv;
#pragma unroll
            for (int d = 0; d < EDIM_; ++d) a5[d] += wv * ea[d];
        }
        if (c < 4) { src_c[c] = src; a_c[c] = wv; }
        else if (t < cnt) alpha[start + t] = wv;
    }
#pragma unroll
    for (int off = 8; off; off >>= 1) {
        lsum += __shfl_xor(lsum, off);
#pragma unroll
        for (int d = 0; d < EDIM_; ++d) a5[d] += __shfl_xor(a5[d], off);
    }
    float inv = (lsum > 0.f) ? 1.f / lsum : 0.f;
    float e5[EDIM_];
#pragma unroll
    for (int d = 0; d < EDIM_; ++d) e5[d] = a5[d] * inv;

    float acc[8] = {};
    for (int c = 0; c < nch; ++c) {
        int src; float a;
        if (c < 4) { src = src_c[c]; a = a_c[c]; }
        else {
            int t = c * 16 + lane;
            if (t < cnt) {
                int e = eid_dst[start + t];
                src = ei[e];
                a = alpha[start + t];
            } else { src = 0; a = 0.f; }
        }
        int m = min(16, cnt - c * 16);
        if (m == 16) {
#pragma unroll
            for (int j = 0; j < 16; ++j) {
                int   sj = __shfl(src, gbase + j);
                float aj = __shfl(a,   gbase + j);
                s16x8 v = *(const s16x8*)(qkvs + (long)sj * 512 + 256 + lane * 8);
#pragma unroll
                for (int k = 0; k < 8; ++k) acc[k] += aj * bf2f(v[k]);
            }
        } else {
            for (int j = 0; j < m; ++j) {
                int   sj = __shfl(src, gbase + j);
                float aj = __shfl(a,   gbase + j);
                s16x8 v = *(const s16x8*)(qkvs + (long)sj * 512 + 256 + lane * 8);
#pragma unroll
                for (int k = 0; k < 8; ++k) acc[k] += aj * bf2f(v[k]);
            }
        }
    }

    s16x8 sk = *(const s16x8*)(qkvs + (long)node * 512 + 384 + lane * 8);
    s16x8 o;
#pragma unroll
    for (int j = 0; j < 8; ++j) {
        float ec = 0.f;
#pragma unroll
        for (int d = 0; d < EDIM_; ++d) ec += e5[d] * sWe[d * 128 + lane * 8 + j];
        float val = acc[j] * inv + ec + bf2f(sk[j]);
        o[j] = f2bf(fmaxf(val, 0.f));
    }
    *(s16x8*)(h + (long)node * 128 + lane * 8) = o;
}

// ---------------------------------------------------------------------------
// T1 = A @ s1b computed SPARSELY over edges (src-CSR, XCD-swizzled)
// ---------------------------------------------------------------------------
__global__ __launch_bounds__(256) void t1_gather_kernel(const int* __restrict__ ei,
                                                        const int* __restrict__ rp_src,
                                                        const int* __restrict__ deg_src,
                                                        const int* __restrict__ eid_src,
                                                        const short* __restrict__ s1b,
                                                        short* __restrict__ T1s) {
    int g = threadIdx.x >> 4;
    int lane = threadIdx.x & 15;
    int gbase = (threadIdx.x & 63) & ~15;
    int b = blockIdx.x;
    int xcd = b & 7, idx = b >> 3;
    int nb = (xcd * 8 + (idx >> 5)) * 32 + (idx & 31);
    int node = nb * 16 + g;

    int start = rp_src[node], cnt = deg_src[node];
    int nch = (cnt + 15) >> 4;
    float acc[16] = {};
    for (int c = 0; c < nch; ++c) {
        int t = c * 16 + lane;
        int dst = 0;
        if (t < cnt) {
            int e = eid_src[start + t];
            dst = ei[EDGES + e];
        }
        int m = min(16, cnt - c * 16);
        if (m == 16) {
#pragma unroll
            for (int j = 0; j < 16; ++j) {
                int dj = __shfl(dst, gbase + j);
                const s16x8* p = (const s16x8*)(s1b + (long)dj * 256 + lane * 16);
                s16x8 v0 = p[0], v1 = p[1];
#pragma unroll
                for (int k = 0; k < 8; ++k) { acc[k] += bf2f(v0[k]); acc[8 + k] += bf2f(v1[k]); }
            }
        } else {
            for (int j = 0; j < m; ++j) {
                int dj = __shfl(dst, gbase + j);
                const s16x8* p = (const s16x8*)(s1b + (long)dj * 256 + lane * 16);
                s16x8 v0 = p[0], v1 = p[1];
#pragma unroll
                for (int k = 0; k < 8; ++k) { acc[k] += bf2f(v0[k]); acc[8 + k] += bf2f(v1[k]); }
            }
        }
    }
    s16x8 o0, o1;
#pragma unroll
    for (int k = 0; k < 8; ++k) { o0[k] = f2bf(acc[k]); o1[k] = f2bf(acc[8 + k]); }
    short* o = T1s + (long)node * 256 + lane * 16;
    *(s16x8*)(o)     = o0;
    *(s16x8*)(o + 8) = o1;
}

// ---------------------------------------------------------------------------
// Readout — g = gsum/128 (column sums accumulated by fused_gc3 COLSUM)
// ---------------------------------------------------------------------------
__global__ __launch_bounds__(128) void readout_kernel(const float* __restrict__ gsum,
                                                      const float* __restrict__ W_lin1,
                                                      const float* __restrict__ b_lin1,
                                                      const float* __restrict__ W_ro,
                                                      const float* __restrict__ b_ro,
                                                      float* __restrict__ out) {
    int b = blockIdx.x, t = threadIdx.x;
    __shared__ float g[128], g2[128], wred[2];
    g[t] = gsum[(long)b * 128 + t] * (1.f / (float)K2C);
    __syncthreads();
    float u = b_lin1[t];
    for (int k = 0; k < 128; ++k) u += g[k] * W_lin1[k * 128 + t];
    g2[t] = fmaxf(u, 0.f);
    __syncthreads();
    float p = g2[t] * W_ro[t];
#pragma unroll
    for (int off = 32; off; off >>= 1) p += __shfl_xor(p, off);
    if ((t & 63) == 0) wred[t >> 6] = p;
    __syncthreads();
    if (t == 0) {
        float tot = wred[0] + wred[1] + b_ro[0];
        out[b] = 1.f / (1.f + expf(-tot));
    }
}

// ---------------------------------------------------------------------------
extern "C" void kernel_launch(void* const* d_in, const int* in_sizes, int n_in,
                              void* d_out, int out_size, void* d_ws, size_t ws_size,
                              hipStream_t stream) {
    const float* x      = (const float*)d_in[0];
    const int*   ei     = (const int*)d_in[1];
    const float* eattr  = (const float*)d_in[2];
    const float* gamma  = (const float*)d_in[4];
    const float* beta   = (const float*)d_in[5];
    const float* Wq     = (const float*)d_in[6];
    const float* bq     = (const float*)d_in[7];
    const float* Wk     = (const float*)d_in[8];
    const float* bk     = (const float*)d_in[9];
    const float* Wv     = (const float*)d_in[10];
    const float* bv     = (const float*)d_in[11];
    const float* We     = (const float*)d_in[12];
    const float* Wskip  = (const float*)d_in[13];
    const float* bskip  = (const float*)d_in[14];
    const float* W_mlp1 = (const float*)d_in[15];
    const float* b_mlp1 = (const float*)d_in[16];
    const float* W2_rel = (const float*)d_in[17];
    const float* b2_rel = (const float*)d_in[18];
    const float* W2_root= (const float*)d_in[19];
    const float* W_mlp2 = (const float*)d_in[20];
    const float* b_mlp2 = (const float*)d_in[21];
    const float* W3_rel = (const float*)d_in[22];
    const float* b3_rel = (const float*)d_in[23];
    const float* W3_root= (const float*)d_in[24];
    const float* W_lin1 = (const float*)d_in[25];
    const float* b_lin1 = (const float*)d_in[26];
    const float* W_ro   = (const float*)d_in[27];
    const float* b_ro   = (const float*)d_in[28];
    float* out = (float*)d_out;

    char* w = (char*)d_ws;
    const size_t MB = 1ull << 20;
    // Workspace, lifetime-aliased (round-9 layout).
    short* qkvs = (short*)(w + 0);          // [NTOT,512] bf16 32MB (dead after step 6)
    short* S    = (short*)(w + 32 * MB);    // [NTOT,512] bf16 32MB (steps 5-6)
    short* T1s  = (short*)(w + 48 * MB);    // [NTOT,256] bf16 16MB (steps 8-9, over dead S hi)
    short* s1b  = (short*)(w + 64 * MB);    // [NTOT,256] bf16 16MB
    short* xd2  = (short*)(w + 56 * MB);    // [B,256,128] bf16 4MB
    short* s2b  = (short*)(w + 72 * MB);    // [B,256,128] bf16 4MB
    float* t2   = (float*)(w + 64 * MB);    // [B,256,128] fp32 8MB
    float* adj2 = (float*)(w + 0);          // [B,128,128] 4MB (raw)
    float* xp2  = (float*)(w + 4 * MB);     // [B,128,128] 4MB
    float* adj1 = (float*)(w + 80 * MB);    // [B,256,256] 16MB (raw)
    float* xp1  = (float*)(w + 96 * MB);    // [B,256,128] 8MB
    float* alpha= (float*)(w + 97 * MB);    // [EDGES] fp32 2MB (overflow spill; dead
                                            //  after attn_pv, before xp1 written)
    short* h    = (short*)(w + 112 * MB);   // [NTOT,128] bf16 8MB (steps 6-pool1)
    char* misc  = w + 104 * MB;
    short* W4b    = (short*)(misc + 0x00000);   // [128,512] bf16 (pre-packed)
    float* bias4  = (float*)(misc + 0x40000);
    float* scale  = (float*)(misc + 0x41400);
    float* shift  = (float*)(misc + 0x41600);
    float* rowsum1= (float*)(misc + 0x42000);   // [B,256] fp32 64KB (zeroed)
    float* rowsum2= (float*)(misc + 0x52000);   // [B,128] fp32 32KB (zeroed)
    int* deg_src  = (int*)(misc + 0x60000);
    int* deg_dst  = (int*)(misc + 0x80000);
    int* rp_src   = (int*)(misc + 0xA0000);
    int* rp_dst   = (int*)(misc + 0xC0000);
    int* eid_src  = (int*)(misc + 0x120000);
    int* eid_dst  = (int*)(misc + 0x320000);
    float* psum   = (float*)(misc + 0x520000);
    float* psq    = (float*)(misc + 0x540000);
    float* gsum   = (float*)(misc + 0x560000);  // [B,128] fp32 32KB (zeroed in fin)

    // Zero rowsum1 + rowsum2 only.
    hipMemsetAsync(misc + 0x42000, 0, 0x18000, stream);

    // 1. MERGED: BN stats + weight pack (W4 packed as bf16)
    prep_kernel<<<512, 256, 0, stream>>>(x, psum, psq,
                                         Wq, Wk, Wv, Wskip, bq, bk, bv, bskip,
                                         W4b, bias4);

    // 2. BN finalize + gsum zero
    fin_kernel<<<1, 1024, 0, stream>>>(psum, psq, gamma, beta, scale, shift, gsum);

    // 3. MERGED: qkvs GEMM (BBF16 weight staging) ∥ per-graph LDS CSR build
    qkvs_csr_kernel<<<1152, 256, 0, stream>>>(x, W4b, bias4, qkvs, scale, shift,
                                              ei, rp_src, deg_src, eid_src,
                                              rp_dst, deg_dst, eid_dst);

    // 4. S(bf16) = (Q @ K^T) / sqrt(H) per graph (dense MFMA, XCD-aligned)
    bgemm<true><<<dim3(4, 4, BGRAPH), 256, 0, stream>>>(
        qkvs + 0, qkvs + 128, S, 0.08838834764831845f,
        NNODE, NNODE, 128, 512, 512, 512,
        (long)NNODE * 512, (long)NNODE * 512, (long)NNODE * NNODE);

    // 5. FUSED edge-softmax + PV gather -> h(bf16)
    attn_pv_kernel<<<NTOT / 16, 256, 0, stream>>>(
        S, ei, eattr, We, rp_dst, deg_dst, eid_dst, qkvs, alpha, h);

    // 6. s1b(bf16) = softmax_row(h @ W_mlp1 + b)
    mlp_softmax_kernel<K1C><<<NTOT / 64, 256, 0, stream>>>(h, W_mlp1, b_mlp1, s1b);

    // 7. T1(bf16) = A @ s1b via sparse edge gather (src-CSR)
    t1_gather_kernel<<<NTOT / 16, 256, 0, stream>>>(
        ei, rp_src, deg_src, eid_src, s1b, T1s);

    // 8. MERGED pool1: xp1 = s1b^T h ∥ adj1(raw) = s1b^T T1s (+ROWSUM)
    pool1_kernel<<<768, 256, 0, stream>>>(s1b, h, T1s, xp1, adj1, rowsum1);

    // 9. FUSED GraphConv2: xd2 = relu([adjN1@xp1 | xp1]@[W2_rel;W2_root]+b)
    fused_gc_kernel<K1C, true, true, false><<<dim3(4, BGRAPH), 256, 0, stream>>>(
        adj1, rowsum1, xp1, W2_rel, b2_rel, W2_root, xd2);

    // 10. s2b(bf16) = softmax_row(xd2 @ W_mlp2 + b)
    mlp_softmax_kernel<K2C><<<(BGRAPH * K1C) / 64, 256, 0, stream>>>(xd2, W_mlp2, b_mlp2, s2b);

    // 11. MERGED pool2: t2 = adjN1@s2b (ANORM) ∥ xp2 = s2b^T xd2
    pool2_kernel<<<768, 256, 0, stream>>>(adj1, rowsum1, s2b, xd2, t2, xp2);

    // 12. adj2(raw) = s2b^T t2 (+ROWSUM -> rowsum2)
    mgemm<64, true, false, false, true, false, false, false, false, false, true, false>
        <<<dim3(2, 2, BGRAPH), 256, 0, stream>>>(
        s2b, t2, nullptr, nullptr, 0, nullptr, adj2, nullptr, rowsum2,
        K2C, K2C, K1C, K2C, K2C, K2C,
        (long)K1C * K2C, (long)K1C * K2C, (long)K2C * K2C);

    // 13. FUSED GraphConv3 + COLSUM -> gsum (xd3 never materialized)
    fused_gc_kernel<K2C, false, false, true><<<dim3(2, BGRAPH), 256, 0, stream>>>(
        adj2, rowsum2, xp2, W3_rel, b3_rel, W3_root, gsum);

    // 14. Readout from gsum
    readout_kernel<<<BGRAPH, 128, 0, stream>>>(gsum, W_lin1, b_lin1, W_ro, b_ro, out);

    (void)in_sizes; (void)n_in; (void)out_size; (void)ws_size;
}

// Round 14
// 419.112 us; speedup vs baseline: 1.0155x; 1.0155x over previous
//
#include <hip/hip_runtime.h>
#include <math.h>

// Problem constants
#define BGRAPH 64
#define NNODE  512
#define NTOT   32768        // BGRAPH*NNODE
#define CIN    128
#define HDIM   128
#define EDIM_  5
#define EDGES  524288
#define EPG    8192         // edges per graph
#define K1C    256
#define K2C    128

using f32x4 = __attribute__((ext_vector_type(4))) float;
using s16x8 = __attribute__((ext_vector_type(8))) short;

__device__ __forceinline__ short f2bf(float f) {
    union { float f; unsigned u; } v; v.f = f;
    unsigned r = v.u + 0x7fffu + ((v.u >> 16) & 1u);   // RNE
    return (short)(r >> 16);
}
__device__ __forceinline__ float bf2f(short s) {
    union { unsigned u; float f; } v; v.u = ((unsigned)(unsigned short)s) << 16;
    return v.f;
}

// ---------------------------------------------------------------------------
// MERGED prep: BatchNorm stats (blocks 0..255) + weight pack (256..511).
// W4 packed directly as bf16 (f2bf applied once here).
// ---------------------------------------------------------------------------
__global__ __launch_bounds__(256) void prep_kernel(const float* __restrict__ x,
                                                   float* __restrict__ psum,
                                                   float* __restrict__ psq,
                                                   const float* __restrict__ Wq, const float* __restrict__ Wk,
                                                   const float* __restrict__ Wv, const float* __restrict__ Ws,
                                                   const float* __restrict__ bq, const float* __restrict__ bk,
                                                   const float* __restrict__ bv, const float* __restrict__ bs,
                                                   short* __restrict__ W4b, float* __restrict__ bias4) {
    __shared__ float ss[128], sq[128];
    int tid = threadIdx.x, bid = blockIdx.x;
    if (bid < 256) {
        long idx0 = (long)bid * 256 + tid;
        float4 s = {0.f, 0.f, 0.f, 0.f}, q = {0.f, 0.f, 0.f, 0.f};
#pragma unroll
        for (int it = 0; it < 16; ++it) {
            float4 v = *(const float4*)(x + (idx0 + (long)it * 65536) * 4);
            s.x += v.x; s.y += v.y; s.z += v.z; s.w += v.w;
            q.x += v.x * v.x; q.y += v.y * v.y; q.z += v.z * v.z; q.w += v.w * v.w;
        }
        if (tid < 128) { ss[tid] = 0.f; sq[tid] = 0.f; }
        __syncthreads();
        int c0 = (tid & 31) * 4;
        atomicAdd(&ss[c0 + 0], s.x); atomicAdd(&ss[c0 + 1], s.y);
        atomicAdd(&ss[c0 + 2], s.z); atomicAdd(&ss[c0 + 3], s.w);
        atomicAdd(&sq[c0 + 0], q.x); atomicAdd(&sq[c0 + 1], q.y);
        atomicAdd(&sq[c0 + 2], q.z); atomicAdd(&sq[c0 + 3], q.w);
        __syncthreads();
        if (tid < 128) {
            psum[bid * 128 + tid] = ss[tid];
            psq[bid * 128 + tid]  = sq[tid];
        }
    } else {
        int i = (bid - 256) * 256 + tid;
        if (i < 128 * 512) {
            int k = i / 512, j = i % 512;
            float v;
            if (j < 128)      v = Wq[k * 128 + j];
            else if (j < 256) v = Wk[k * 128 + (j - 128)];
            else if (j < 384) v = Wv[k * 128 + (j - 256)];
            else              v = Ws[k * 128 + (j - 384)];
            W4b[i] = f2bf(v);
        }
        if (i < 512) {
            float v;
            if (i < 128)      v = bq[i];
            else if (i < 256) v = bk[i - 128];
            else if (i < 384) v = bv[i - 256];
            else              v = bs[i - 384];
            bias4[i] = v;
        }
    }
}

// ---------------------------------------------------------------------------
// BatchNorm finalize + gsum zero (1 block).
// ---------------------------------------------------------------------------
__global__ __launch_bounds__(1024) void fin_kernel(const float* __restrict__ psum,
                                                   const float* __restrict__ psq,
                                                   const float* __restrict__ gamma,
                                                   const float* __restrict__ beta,
                                                   float* __restrict__ scale,
                                                   float* __restrict__ shift,
                                                   float* __restrict__ gsum) {
    int tid = threadIdx.x;
    if (tid < 128) {
        int c = tid;
        float s = 0.f, q = 0.f;
        for (int b = 0; b < 256; ++b) { s += psum[b * 128 + c]; q += psq[b * 128 + c]; }
        float mu  = s / (float)NTOT;
        float var = q / (float)NTOT - mu * mu;
        float rstd = rsqrtf(var + 1e-5f);
        float sc = gamma[c] * rstd;
        scale[c] = sc;
        shift[c] = beta[c] - mu * sc;
    }
    for (int i = tid; i < BGRAPH * 128; i += 1024) gsum[i] = 0.f;
}

// ---------------------------------------------------------------------------
// BF16 MFMA GEMM body (device), tile TILE x TILE (128 or 64), BK=32.
//   AU8: A uint8. ATRBF16: TRANS_A bf16 A. ABF16: !TRANS_A bf16 A.
//   BBF16: B bf16. OBF16: bf16 out. DUAL: concat-K second source.
//   ANORM: A is raw pooled adjacency; apply (r==c?0:v*dinv[r]*dinv[c]) at
//   staging; dvl (LDS) filled from `scale` = rowsum buffer (stride lda).
//   ROWSUM: epilogue accumulates per-row sums of C (diag excluded) into
//   (float*)shift via deterministic shfl reduce + commutative atomics.
// Block coords passed explicitly so merged wrappers can remap blocks.
// ---------------------------------------------------------------------------
template <int TILE, bool TRANS_A, bool AFFINE, bool ANORM, bool ROWSUM, bool RELU,
          bool DUAL, bool OBF16, bool AU8, bool BBF16, bool ATRBF16, bool ABF16>
__device__ __forceinline__ void mgemm_body(short* As, short* Bs, float* dvl,
                                           const void* __restrict__ Av,
                                           const void* __restrict__ Bv,
                                           const void* __restrict__ A2v,
                                           const void* __restrict__ B2v,
                                           int Ksplit,
                                           const float* __restrict__ bias,
                                           void* __restrict__ Cv,
                                           const float* __restrict__ scale,
                                           const float* __restrict__ shift,
                                           int M, int Nc, int K,
                                           int lda, int ldb, int ldc,
                                           long sA, long sB, long sC,
                                           int bx, int by, int bz) {
    constexpr int ASZ = AU8 ? 1 : ((ATRBF16 || ABF16) ? 2 : 4);
    constexpr int BSZ = BBF16 ? 2 : 4;
    const char* Abase = (const char*)Av + (long)bz * sA * ASZ;
    const char* Bbase = (const char*)Bv + (long)bz * sB * BSZ;
    float* C = (float*)Cv + (OBF16 ? 0 : (long)bz * sC);
    short* Cs = (short*)Cv + (OBF16 ? (long)bz * sC : 0);
    const int m0 = by * TILE, n0 = bx * TILE;
    const int tid = threadIdx.x;
    const int lane16 = tid & 15;
    const int quad = (tid & 63) >> 4;
    const int wrow = (tid >> 6) >> 1, wcol = (tid >> 6) & 1;
    constexpr int WT = TILE / 32;

    if (ANORM) {
        for (int i = tid; i < K; i += 256)
            dvl[i] = 1.f / (sqrtf(scale[(long)bz * lda + i]) + 1e-15f);
        __syncthreads();
    }

    f32x4 acc[WT][WT] = {};

    for (int k0 = 0; k0 < K; k0 += 32) {
        const char* Au = Abase; const char* Bu = Bbase; int ku = k0;
        if (DUAL && k0 >= Ksplit) { Au = (const char*)A2v; Bu = (const char*)B2v; ku = k0 - Ksplit; }

        if (!TRANS_A) {
#pragma unroll
            for (int p = 0; p < TILE / 32; ++p) {
                int idx = tid + p * 256;
                int row = idx >> 3, c4 = idx & 7;
                short4 o;
                if (AU8) {
                    unsigned u = *(const unsigned*)((const unsigned char*)Au +
                                                    (long)(m0 + row) * lda + ku + c4 * 4);
                    o = make_short4(f2bf((float)(u & 255u)), f2bf((float)((u >> 8) & 255u)),
                                    f2bf((float)((u >> 16) & 255u)), f2bf((float)((u >> 24) & 255u)));
                } else if (ABF16) {
                    o = *(const short4*)((const short*)Au + (long)(m0 + row) * lda + ku + c4 * 4);
                } else {
                    float4 v = *(const float4*)((const float*)Au + (long)(m0 + row) * lda + ku + c4 * 4);
                    if (AFFINE) {
                        int k = ku + c4 * 4;
                        v.x = v.x * scale[k] + shift[k];
                        v.y = v.y * scale[k + 1] + shift[k + 1];
                        v.z = v.z * scale[k + 2] + shift[k + 2];
                        v.w = v.w * scale[k + 3] + shift[k + 3];
                    }
                    if (ANORM) {
                        int k = ku + c4 * 4;
                        int grow = m0 + row;
                        float dr = dvl[grow];
                        v.x = (grow == k + 0) ? 0.f : v.x * dr * dvl[k + 0];
                        v.y = (grow == k + 1) ? 0.f : v.y * dr * dvl[k + 1];
                        v.z = (grow == k + 2) ? 0.f : v.z * dr * dvl[k + 2];
                        v.w = (grow == k + 3) ? 0.f : v.w * dr * dvl[k + 3];
                    }
                    o = make_short4(f2bf(v.x), f2bf(v.y), f2bf(v.z), f2bf(v.w));
                }
                *(short4*)&As[row * 40 + c4 * 4] = o;
            }
        } else {
            if (TILE == 128 || tid < 128) {
                int c4 = tid >> 3, g = tid & 7;        // row-group slow, k-group fast
                short* d = &As[(c4 * 4) * 40 + g * 4];
                if (ATRBF16) {
                    const short* src = (const short*)Au + (long)(ku + g * 4) * lda + m0 + c4 * 4;
                    short4 r0 = *(const short4*)(src);
                    short4 r1 = *(const short4*)(src + lda);
                    short4 r2 = *(const short4*)(src + 2 * lda);
                    short4 r3 = *(const short4*)(src + 3 * lda);
                    *(short4*)(d + 0 * 40) = make_short4(r0.x, r1.x, r2.x, r3.x);
                    *(short4*)(d + 1 * 40) = make_short4(r0.y, r1.y, r2.y, r3.y);
                    *(short4*)(d + 2 * 40) = make_short4(r0.z, r1.z, r2.z, r3.z);
                    *(short4*)(d + 3 * 40) = make_short4(r0.w, r1.w, r2.w, r3.w);
                } else {
                    const float* src = (const float*)Au + (long)(ku + g * 4) * lda + m0 + c4 * 4;
                    float4 r0 = *(const float4*)(src);
                    float4 r1 = *(const float4*)(src + lda);
                    float4 r2 = *(const float4*)(src + 2 * lda);
                    float4 r3 = *(const float4*)(src + 3 * lda);
                    *(short4*)(d + 0 * 40) = make_short4(f2bf(r0.x), f2bf(r1.x), f2bf(r2.x), f2bf(r3.x));
                    *(short4*)(d + 1 * 40) = make_short4(f2bf(r0.y), f2bf(r1.y), f2bf(r2.y), f2bf(r3.y));
                    *(short4*)(d + 2 * 40) = make_short4(f2bf(r0.z), f2bf(r1.z), f2bf(r2.z), f2bf(r3.z));
                    *(short4*)(d + 3 * 40) = make_short4(f2bf(r0.w), f2bf(r1.w), f2bf(r2.w), f2bf(r3.w));
                }
            }
        }
        if (TILE == 128 || tid < 128) {
            int c4 = tid >> 3, g = tid & 7;            // n-group slow, k-group fast
            short* d = &Bs[(c4 * 4) * 40 + g * 4];
            if (BBF16) {
                const short* src = (const short*)Bu + (long)(ku + g * 4) * ldb + n0 + c4 * 4;
                short4 r0 = *(const short4*)(src);
                short4 r1 = *(const short4*)(src + ldb);
                short4 r2 = *(const short4*)(src + 2 * ldb);
                short4 r3 = *(const short4*)(src + 3 * ldb);
                *(short4*)(d + 0 * 40) = make_short4(r0.x, r1.x, r2.x, r3.x);
                *(short4*)(d + 1 * 40) = make_short4(r0.y, r1.y, r2.y, r3.y);
                *(short4*)(d + 2 * 40) = make_short4(r0.z, r1.z, r2.z, r3.z);
                *(short4*)(d + 3 * 40) = make_short4(r0.w, r1.w, r2.w, r3.w);
            } else {
                const float* src = (const float*)Bu + (long)(ku + g * 4) * ldb + n0 + c4 * 4;
                float4 r0 = *(const float4*)(src);
                float4 r1 = *(const float4*)(src + ldb);
                float4 r2 = *(const float4*)(src + 2 * ldb);
                float4 r3 = *(const float4*)(src + 3 * ldb);
                *(short4*)(d + 0 * 40) = make_short4(f2bf(r0.x), f2bf(r1.x), f2bf(r2.x), f2bf(r3.x));
                *(short4*)(d + 1 * 40) = make_short4(f2bf(r0.y), f2bf(r1.y), f2bf(r2.y), f2bf(r3.y));
                *(short4*)(d + 2 * 40) = make_short4(f2bf(r0.z), f2bf(r1.z), f2bf(r2.z), f2bf(r3.z));
                *(short4*)(d + 3 * 40) = make_short4(f2bf(r0.w), f2bf(r1.w), f2bf(r2.w), f2bf(r3.w));
            }
        }
        __syncthreads();

        s16x8 af[WT], bf[WT];
#pragma unroll
        for (int t = 0; t < WT; ++t) {
            af[t] = *(const s16x8*)&As[(wrow * (TILE / 2) + t * 16 + lane16) * 40 + quad * 8];
            bf[t] = *(const s16x8*)&Bs[(wcol * (TILE / 2) + t * 16 + lane16) * 40 + quad * 8];
        }
#pragma unroll
        for (int i = 0; i < WT; ++i)
#pragma unroll
            for (int j = 0; j < WT; ++j)
                acc[i][j] = __builtin_amdgcn_mfma_f32_16x16x32_bf16(af[i], bf[j], acc[i][j], 0, 0, 0);
        __syncthreads();
    }

#pragma unroll
    for (int i = 0; i < WT; ++i) {
        int gm = m0 + wrow * (TILE / 2) + i * 16 + quad * 4;
#pragma unroll
        for (int j = 0; j < WT; ++j) {
            int gn = n0 + wcol * (TILE / 2) + j * 16 + lane16;
            float bv = bias ? bias[gn] : 0.f;
#pragma unroll
            for (int r = 0; r < 4; ++r) {
                float val = acc[i][j][r] + bv;
                if (RELU) val = fmaxf(val, 0.f);
                if (OBF16) Cs[(long)(gm + r) * ldc + gn] = f2bf(val);
                else       C[(long)(gm + r) * ldc + gn] = val;
            }
        }
    }

    if (ROWSUM) {
        float* rlA = (float*)As;
        float* rlB = (float*)Bs;
#pragma unroll
        for (int i = 0; i < WT; ++i) {
#pragma unroll
            for (int r = 0; r < 4; ++r) {
                int gm = m0 + wrow * (TILE / 2) + i * 16 + quad * 4 + r;
                float p = 0.f;
#pragma unroll
                for (int j = 0; j < WT; ++j) {
                    int gn = n0 + wcol * (TILE / 2) + j * 16 + lane16;
                    p += (gn == gm) ? 0.f : acc[i][j][r];
                }
#pragma unroll
                for (int off = 1; off < 16; off <<= 1) p += __shfl_xor(p, off);
                if (lane16 == 0) {
                    int rl = wrow * (TILE / 2) + i * 16 + quad * 4 + r;
                    (wcol ? rlB : rlA)[rl] = p;
                }
            }
        }
        __syncthreads();
        float* rout = (float*)shift;
        for (int t = tid; t < TILE; t += 256)
            atomicAdd(&rout[(long)bz * M + m0 + t], rlA[t] + rlB[t]);
    }
}

// Standalone wrapper (used for adj2)
template <int TILE, bool TRANS_A, bool AFFINE, bool ANORM, bool ROWSUM, bool RELU,
          bool DUAL, bool OBF16, bool AU8, bool BBF16, bool ATRBF16, bool ABF16>
__global__ __launch_bounds__(256) void mgemm(const void* __restrict__ Av,
                                             const void* __restrict__ Bv,
                                             const void* __restrict__ A2v,
                                             const void* __restrict__ B2v,
                                             int Ksplit,
                                             const float* __restrict__ bias,
                                             void* __restrict__ Cv,
                                             const float* __restrict__ scale,
                                             const float* __restrict__ shift,
                                             int M, int Nc, int K,
                                             int lda, int ldb, int ldc,
                                             long sA, long sB, long sC) {
    __shared__ __align__(16) short As[TILE * 40];
    __shared__ __align__(16) short Bs[TILE * 40];
    __shared__ float dvl[ANORM ? 256 : 1];
    mgemm_body<TILE, TRANS_A, AFFINE, ANORM, ROWSUM, RELU, DUAL, OBF16, AU8, BBF16, ATRBF16, ABF16>(
        As, Bs, dvl, Av, Bv, A2v, B2v, Ksplit, bias, Cv, scale, shift,
        M, Nc, K, lda, ldb, ldc, sA, sB, sC,
        blockIdx.x, blockIdx.y, blockIdx.z);
}

// ---------------------------------------------------------------------------
// Per-graph LDS CSR build (one block per graph+direction): histogram via LDS
// atomics, 512-entry LDS scan, then scatter eid DIRECTLY to global (positions
// from LDS cursors — no global atomics; each graph's 32KB eid span is written
// by a single block so lines stay L2-private, one writeback).
// smemInt layout: cnt[512] | part[256]  (3072 B)
// ---------------------------------------------------------------------------
__device__ __forceinline__ void csr_build_graph(int* smemInt,
                                                const int* __restrict__ ei_dir,
                                                int gnode0, int gedge0,
                                                int* __restrict__ rp,
                                                int* __restrict__ deg,
                                                int* __restrict__ eid) {
    int* cnt  = smemInt;
    int* part = smemInt + 512;
    int tid = threadIdx.x;
    cnt[tid] = 0; cnt[tid + 256] = 0;
    __syncthreads();
    // histogram
    for (int k = 0; k < EPG / 256; ++k) {
        int e = gedge0 + k * 256 + tid;
        atomicAdd(&cnt[ei_dir[e] & 511], 1);
    }
    __syncthreads();
    // exclusive scan over 512 (thread t owns counters 2t, 2t+1)
    int c0 = cnt[2 * tid], c1 = cnt[2 * tid + 1];
    part[tid] = c0 + c1;
    __syncthreads();
    for (int off = 1; off < 256; off <<= 1) {
        int v = part[tid];
        int add = (tid >= off) ? part[tid - off] : 0;
        __syncthreads();
        part[tid] = v + add;
        __syncthreads();
    }
    int excl = (tid == 0) ? 0 : part[tid - 1];
    rp[gnode0 + 2 * tid]      = gedge0 + excl;
    rp[gnode0 + 2 * tid + 1]  = gedge0 + excl + c0;
    deg[gnode0 + 2 * tid]     = c0;
    deg[gnode0 + 2 * tid + 1] = c1;
    cnt[2 * tid]     = excl;        // becomes local cursor
    cnt[2 * tid + 1] = excl + c0;
    __syncthreads();
    // scatter directly to global (span is block-private -> L2-local)
    for (int k = 0; k < EPG / 256; ++k) {
        int e = gedge0 + k * 256 + tid;
        int pos = atomicAdd(&cnt[ei_dir[e] & 511], 1);
        eid[gedge0 + pos] = e;
    }
}

// ---------------------------------------------------------------------------
// MERGED: per-graph LDS CSR build FIRST (blocks 0..127 — the latency-bound
// long pole starts at t=0 and hides under the GEMM) + qkvs GEMM (128..1151,
// B = pre-packed bf16 W4b). LDS = 20480 B.
// ---------------------------------------------------------------------------
__global__ __launch_bounds__(256) void qkvs_csr_kernel(const float* __restrict__ x,
                                                       const short* __restrict__ W4b,
                                                       const float* __restrict__ bias4,
                                                       short* __restrict__ qkvs,
                                                       const float* __restrict__ scale,
                                                       const float* __restrict__ shift,
                                                       const int* __restrict__ ei,
                                                       int* __restrict__ rp_src,
                                                       int* __restrict__ deg_src,
                                                       int* __restrict__ eid_src,
                                                       int* __restrict__ rp_dst,
                                                       int* __restrict__ deg_dst,
                                                       int* __restrict__ eid_dst) {
    __shared__ __align__(16) char smem[20480];
    int b = blockIdx.x;
    if (b < 128) {
        int g = b >> 1;                      // graph = b>>1, dir = b&1
        if (b & 1)
            csr_build_graph((int*)smem, ei + EDGES, g * NNODE, g * EPG,
                            rp_dst, deg_dst, eid_dst);
        else
            csr_build_graph((int*)smem, ei, g * NNODE, g * EPG,
                            rp_src, deg_src, eid_src);
    } else {
        int gb = b - 128;                    // [0,1024)
        short* As = (short*)smem;
        short* Bs = (short*)(smem + 10240);
        mgemm_body<128, false, true, false, false, false, false, true, false, true, false, false>(
            As, Bs, nullptr, x, W4b, nullptr, nullptr, 0, bias4, qkvs, scale, shift,
            NTOT, 512, 128, 128, 512, 512, 0, 0, 0,
            gb & 3, gb >> 2, 0);
    }
}

// ---------------------------------------------------------------------------
// MERGED pool1: xp1 = s1b^T h (blocks 0..511) ∥ adj1(raw)=s1b^T T1s + ROWSUM
// (blocks 512..767). Outputs disjoint (h at 112MB; adj1 at 80MB).
// ---------------------------------------------------------------------------
__global__ __launch_bounds__(256) void pool1_kernel(const short* __restrict__ s1b,
                                                    const short* __restrict__ h,
                                                    const short* __restrict__ T1s,
                                                    float* __restrict__ xp1,
                                                    float* __restrict__ adj1,
                                                    float* __restrict__ rowsum1) {
    __shared__ __align__(16) short As[128 * 40];
    __shared__ __align__(16) short Bs[128 * 40];
    int b = blockIdx.x;
    if (b < 512) {
        mgemm_body<64, true, false, false, false, false, false, false, false, true, true, false>(
            As, Bs, nullptr, s1b, h, nullptr, nullptr, 0, nullptr, xp1, nullptr, nullptr,
            K1C, 128, NNODE, K1C, 128, 128,
            (long)NNODE * K1C, (long)NNODE * 128, (long)K1C * 128,
            b & 1, (b >> 1) & 3, b >> 3);
    } else {
        int j = b - 512;
        mgemm_body<128, true, false, false, true, false, false, false, false, true, true, false>(
            As, Bs, nullptr, s1b, T1s, nullptr, nullptr, 0, nullptr, adj1, nullptr, rowsum1,
            K1C, K1C, NNODE, K1C, K1C, K1C,
            (long)NNODE * K1C, (long)NNODE * K1C, (long)K1C * K1C,
            j & 1, (j >> 1) & 1, j >> 2);
    }
}

// ---------------------------------------------------------------------------
// MERGED pool2: t2 = adjN1@s2b (ANORM, blocks 0..511) ∥ xp2 = s2b^T xd2
// (blocks 512..767). Outputs disjoint (t2@64MB, xp2@4MB).
// ---------------------------------------------------------------------------
__global__ __launch_bounds__(256) void pool2_kernel(const float* __restrict__ adj1,
                                                    const float* __restrict__ rowsum1,
                                                    const short* __restrict__ s2b,
                                                    const short* __restrict__ xd2,
                                                    float* __restrict__ t2,
                                                    float* __restrict__ xp2) {
    __shared__ __align__(16) short As[64 * 40];
    __shared__ __align__(16) short Bs[64 * 40];
    __shared__ float dvl[256];
    int b = blockIdx.x;
    if (b < 512) {
        mgemm_body<64, false, false, true, false, false, false, false, false, true, false, false>(
            As, Bs, dvl, adj1, s2b, nullptr, nullptr, 0, nullptr, t2, rowsum1, nullptr,
            K1C, K2C, K1C, K1C, K2C, K2C,
            (long)K1C * K1C, (long)K1C * K2C, (long)K1C * K2C,
            b & 1, (b >> 1) & 3, b >> 3);
    } else {
        int j = b - 512;
        mgemm_body<64, true, false, false, false, false, false, false, false, true, true, false>(
            As, Bs, nullptr, s2b, xd2, nullptr, nullptr, 0, nullptr, xp2, nullptr, nullptr,
            K2C, 128, K1C, K2C, 128, 128,
            (long)K1C * K2C, (long)K1C * 128, (long)K2C * 128,
            j & 1, (j >> 1) & 1, j >> 2);
    }
}

// ---------------------------------------------------------------------------
// FUSED DenseGraphConv: Out = act( adjN@xp @ Wrel + xp @ Wroot + b )
// adjN normalized on the fly from raw adj + rowsum (dinv staged in LDS).
// COLSUM: instead of storing Out, accumulate per-graph column sums (bias
// included) into (float*)Outv = gsum[B][128] — feeds the readout mean.
// ---------------------------------------------------------------------------
template <int KADJ, bool RELU, bool OBF16, bool COLSUM>
__global__ __launch_bounds__(256) void fused_gc_kernel(const float* __restrict__ adj,
                                                       const float* __restrict__ rowsum,
                                                       const float* __restrict__ xp,
                                                       const float* __restrict__ Wrel,
                                                       const float* __restrict__ brel,
                                                       const float* __restrict__ Wroot,
                                                       void* __restrict__ Outv) {
    __shared__ __align__(16) short As[64 * 40];
    __shared__ __align__(16) short Bs[128 * 40];
    __shared__ __align__(16) short Tl[64][136];
    __shared__ float dvl[KADJ];
    __shared__ float cs[COLSUM ? 128 : 1];
    const int z = blockIdx.y;
    const int m0 = blockIdx.x * 64;
    const int tid = threadIdx.x;
    const int lane16 = tid & 15;
    const int quad = (tid & 63) >> 4;
    const int wrow = (tid >> 6) >> 1, wcol = (tid >> 6) & 1;
    const float* adjz = adj + (long)z * KADJ * KADJ;
    const float* xpz  = xp + (long)z * KADJ * 128;

    for (int i = tid; i < KADJ; i += 256)
        dvl[i] = 1.f / (sqrtf(rowsum[(long)z * KADJ + i]) + 1e-15f);
    if (COLSUM) for (int i = tid; i < 128; i += 256) cs[i] = 0.f;
    __syncthreads();

    // ---- phase 1: T[64][128] = adjN[m0..m0+64) @ xp ----
    f32x4 acc[2][4] = {};
    for (int k0 = 0; k0 < KADJ; k0 += 32) {
#pragma unroll
        for (int p = 0; p < 2; ++p) {
            int idx = tid + p * 256;
            int row = idx >> 3, c4 = idx & 7;
            int grow = m0 + row, k = k0 + c4 * 4;
            float4 v = *(const float4*)(adjz + (long)grow * KADJ + k);
            float dr = dvl[grow];
            v.x = (grow == k + 0) ? 0.f : v.x * dr * dvl[k + 0];
            v.y = (grow == k + 1) ? 0.f : v.y * dr * dvl[k + 1];
            v.z = (grow == k + 2) ? 0.f : v.z * dr * dvl[k + 2];
            v.w = (grow == k + 3) ? 0.f : v.w * dr * dvl[k + 3];
            *(short4*)&As[row * 40 + c4 * 4] =
                make_short4(f2bf(v.x), f2bf(v.y), f2bf(v.z), f2bf(v.w));
        }
        {
            int c4 = tid >> 3, g = tid & 7;
            short* d = &Bs[(c4 * 4) * 40 + g * 4];
            const float* src = xpz + (long)(k0 + g * 4) * 128 + c4 * 4;
            float4 r0 = *(const float4*)(src);
            float4 r1 = *(const float4*)(src + 128);
            float4 r2 = *(const float4*)(src + 256);
            float4 r3 = *(const float4*)(src + 384);
            *(short4*)(d + 0 * 40) = make_short4(f2bf(r0.x), f2bf(r1.x), f2bf(r2.x), f2bf(r3.x));
            *(short4*)(d + 1 * 40) = make_short4(f2bf(r0.y), f2bf(r1.y), f2bf(r2.y), f2bf(r3.y));
            *(short4*)(d + 2 * 40) = make_short4(f2bf(r0.z), f2bf(r1.z), f2bf(r2.z), f2bf(r3.z));
            *(short4*)(d + 3 * 40) = make_short4(f2bf(r0.w), f2bf(r1.w), f2bf(r2.w), f2bf(r3.w));
        }
        __syncthreads();
        s16x8 af[2], bf[4];
#pragma unroll
        for (int t = 0; t < 2; ++t)
            af[t] = *(const s16x8*)&As[(wrow * 32 + t * 16 + lane16) * 40 + quad * 8];
#pragma unroll
        for (int j = 0; j < 4; ++j)
            bf[j] = *(const s16x8*)&Bs[(wcol * 64 + j * 16 + lane16) * 40 + quad * 8];
#pragma unroll
        for (int t = 0; t < 2; ++t)
#pragma unroll
            for (int j = 0; j < 4; ++j)
                acc[t][j] = __builtin_amdgcn_mfma_f32_16x16x32_bf16(af[t], bf[j], acc[t][j], 0, 0, 0);
        __syncthreads();
    }
#pragma unroll
    for (int t = 0; t < 2; ++t)
#pragma unroll
        for (int j = 0; j < 4; ++j)
#pragma unroll
            for (int r = 0; r < 4; ++r)
                Tl[wrow * 32 + t * 16 + quad * 4 + r][wcol * 64 + j * 16 + lane16] =
                    f2bf(acc[t][j][r]);
    __syncthreads();

    // ---- phase 2: Out = [T | xp_rows] @ [Wrel; Wroot] + b ----
    f32x4 acc2[2][4] = {};
    for (int k0 = 0; k0 < 256; k0 += 32) {
        const bool useXp = (k0 >= 128);
        const float* Wsrc = useXp ? (Wroot + (long)(k0 - 128) * 128)
                                  : (Wrel + (long)k0 * 128);
        {
            int c4 = tid >> 3, g = tid & 7;
            short* d = &Bs[(c4 * 4) * 40 + g * 4];
            const float* src = Wsrc + (long)(g * 4) * 128 + c4 * 4;
            float4 r0 = *(const float4*)(src);
            float4 r1 = *(const float4*)(src + 128);
            float4 r2 = *(const float4*)(src + 256);
            float4 r3 = *(const float4*)(src + 384);
            *(short4*)(d + 0 * 40) = make_short4(f2bf(r0.x), f2bf(r1.x), f2bf(r2.x), f2bf(r3.x));
            *(short4*)(d + 1 * 40) = make_short4(f2bf(r0.y), f2bf(r1.y), f2bf(r2.y), f2bf(r3.y));
            *(short4*)(d + 2 * 40) = make_short4(f2bf(r0.z), f2bf(r1.z), f2bf(r2.z), f2bf(r3.z));
            *(short4*)(d + 3 * 40) = make_short4(f2bf(r0.w), f2bf(r1.w), f2bf(r2.w), f2bf(r3.w));
        }
        if (useXp) {
#pragma unroll
            for (int p = 0; p < 2; ++p) {
                int idx = tid + p * 256;
                int row = idx >> 3, c4 = idx & 7;
                float4 v = *(const float4*)(xpz + (long)(m0 + row) * 128 + (k0 - 128) + c4 * 4);
                *(short4*)&As[row * 40 + c4 * 4] =
                    make_short4(f2bf(v.x), f2bf(v.y), f2bf(v.z), f2bf(v.w));
            }
        }
        __syncthreads();
        s16x8 af[2], bf[4];
#pragma unroll
        for (int t = 0; t < 2; ++t) {
            int ar = wrow * 32 + t * 16 + lane16;
            af[t] = useXp ? *(const s16x8*)&As[ar * 40 + quad * 8]
                          : *(const s16x8*)&Tl[ar][k0 + quad * 8];
        }
#pragma unroll
        for (int j = 0; j < 4; ++j)
            bf[j] = *(const s16x8*)&Bs[(wcol * 64 + j * 16 + lane16) * 40 + quad * 8];
#pragma unroll
        for (int t = 0; t < 2; ++t)
#pragma unroll
            for (int j = 0; j < 4; ++j)
                acc2[t][j] = __builtin_amdgcn_mfma_f32_16x16x32_bf16(af[t], bf[j], acc2[t][j], 0, 0, 0);
        __syncthreads();
    }

    if (!COLSUM) {
        float* Of = (float*)Outv;
        short* Ob = (short*)Outv;
#pragma unroll
        for (int t = 0; t < 2; ++t) {
#pragma unroll
            for (int j = 0; j < 4; ++j) {
                int gcol = wcol * 64 + j * 16 + lane16;
                float bv = brel[gcol];
#pragma unroll
                for (int r = 0; r < 4; ++r) {
                    int grow = m0 + wrow * 32 + t * 16 + quad * 4 + r;
                    float val = acc2[t][j][r] + bv;
                    if (RELU) val = fmaxf(val, 0.f);
                    long oi = ((long)z * KADJ + grow) * 128 + gcol;
                    if (OBF16) Ob[oi] = f2bf(val);
                    else       Of[oi] = val;
                }
            }
        }
    } else {
#pragma unroll
        for (int j = 0; j < 4; ++j) {
            int gcol = wcol * 64 + j * 16 + lane16;
            float bv = brel[gcol];
            float p = 0.f;
#pragma unroll
            for (int t = 0; t < 2; ++t)
#pragma unroll
                for (int r = 0; r < 4; ++r) {
                    float val = acc2[t][j][r] + bv;
                    if (RELU) val = fmaxf(val, 0.f);
                    p += val;
                }
            atomicAdd(&cs[gcol], p);
        }
        __syncthreads();
        float* gsum = (float*)Outv;
        for (int i = tid; i < 128; i += 256)
            atomicAdd(&gsum[(long)z * 128 + i], cs[i]);
    }
}

// ---------------------------------------------------------------------------
// FUSED MLP + row-softmax: Out = softmax_row(A @ W + b), A bf16 [M,128],
// W f32 [128,NC], Out bf16 [M,NC]. TILE_M=64 (4 waves x 16 rows).
// ---------------------------------------------------------------------------
template <int NC>
__global__ __launch_bounds__(256) void mlp_softmax_kernel(const short* __restrict__ A,
                                                          const float* __restrict__ W,
                                                          const float* __restrict__ bias,
                                                          short* __restrict__ Out) {
    __shared__ __align__(16) short As[64 * 40];
    __shared__ __align__(16) short Ws[NC * 40];
    const int tid = threadIdx.x;
    const int lane16 = tid & 15;
    const int quad = (tid & 63) >> 4;
    const int wv = tid >> 6;
    const int m0 = blockIdx.x * 64;
    constexpr int NT = NC / 16;

    f32x4 acc[NT] = {};

    for (int k0 = 0; k0 < 128; k0 += 32) {
        {
            int row = tid >> 2, g = tid & 3;
            *(s16x8*)&As[row * 40 + g * 8] =
                *(const s16x8*)(A + (long)(m0 + row) * 128 + k0 + g * 8);
        }
#pragma unroll
        for (int p = 0; p < NC / 128; ++p) {
            int c4 = tid >> 3, g = tid & 7;
            int n0 = p * 128 + c4 * 4;
            short* d = &Ws[n0 * 40 + g * 4];
            const float* src = W + (long)(k0 + g * 4) * NC + n0;
            float4 r0 = *(const float4*)(src);
            float4 r1 = *(const float4*)(src + NC);
            float4 r2 = *(const float4*)(src + 2 * NC);
            float4 r3 = *(const float4*)(src + 3 * NC);
            *(short4*)(d + 0 * 40) = make_short4(f2bf(r0.x), f2bf(r1.x), f2bf(r2.x), f2bf(r3.x));
            *(short4*)(d + 1 * 40) = make_short4(f2bf(r0.y), f2bf(r1.y), f2bf(r2.y), f2bf(r3.y));
            *(short4*)(d + 2 * 40) = make_short4(f2bf(r0.z), f2bf(r1.z), f2bf(r2.z), f2bf(r3.z));
            *(short4*)(d + 3 * 40) = make_short4(f2bf(r0.w), f2bf(r1.w), f2bf(r2.w), f2bf(r3.w));
        }
        __syncthreads();

        s16x8 af = *(const s16x8*)&As[(wv * 16 + lane16) * 40 + quad * 8];
#pragma unroll
        for (int t = 0; t < NT; ++t) {
            s16x8 bf = *(const s16x8*)&Ws[(t * 16 + lane16) * 40 + quad * 8];
            acc[t] = __builtin_amdgcn_mfma_f32_16x16x32_bf16(af, bf, acc[t], 0, 0, 0);
        }
        __syncthreads();
    }

    float mx[4] = {-INFINITY, -INFINITY, -INFINITY, -INFINITY};
#pragma unroll
    for (int t = 0; t < NT; ++t) {
        float bv = bias[t * 16 + lane16];
#pragma unroll
        for (int r = 0; r < 4; ++r) {
            float x = bf2f(f2bf(acc[t][r] + bv));
            acc[t][r] = x;
            mx[r] = fmaxf(mx[r], x);
        }
    }
#pragma unroll
    for (int off = 8; off; off >>= 1)
#pragma unroll
        for (int r = 0; r < 4; ++r) mx[r] = fmaxf(mx[r], __shfl_xor(mx[r], off));
    float sm[4] = {0.f, 0.f, 0.f, 0.f};
#pragma unroll
    for (int t = 0; t < NT; ++t)
#pragma unroll
        for (int r = 0; r < 4; ++r) {
            float e = expf(acc[t][r] - mx[r]);
            acc[t][r] = e;
            sm[r] += e;
        }
#pragma unroll
    for (int off = 8; off; off >>= 1)
#pragma unroll
        for (int r = 0; r < 4; ++r) sm[r] += __shfl_xor(sm[r], off);
#pragma unroll
    for (int r = 0; r < 4; ++r) sm[r] = 1.f / sm[r];
#pragma unroll
    for (int t = 0; t < NT; ++t)
#pragma unroll
        for (int r = 0; r < 4; ++r)
            Out[(long)(m0 + wv * 16 + quad * 4 + r) * NC + t * 16 + lane16] =
                f2bf(acc[t][r] * sm[r]);
}

// ---------------------------------------------------------------------------
// BF16-input MFMA GEMM (TRANS_B — used for QK^T): C = scale*(A@B^T).
// Block remap: graph z runs on XCD z>>3 (matching attn_pv's consumer swizzle).
// ---------------------------------------------------------------------------
template <bool OBF16>
__global__ __launch_bounds__(256) void bgemm(const short* __restrict__ A,
                                             const short* __restrict__ B,
                                             void* __restrict__ Cv,
                                             float outscale,
                                             int M, int Nc, int K,
                                             int lda, int ldb, int ldc,
                                             long sA, long sB, long sC) {
    __shared__ __align__(16) short As[128 * 40];
    __shared__ __align__(16) short Bs[128 * 40];
    int L = blockIdx.x + (blockIdx.y << 2) + (blockIdx.z << 4);
    int xcd = L & 7, i = L >> 3;
    const int z = xcd * 8 + (i >> 4);
    const int m0 = ((i >> 2) & 3) * 128, n0 = (i & 3) * 128;
    A += (long)z * sA;
    B += (long)z * sB;
    float* C = (float*)Cv + (OBF16 ? 0 : (long)z * sC);
    short* Cs = (short*)Cv + (OBF16 ? (long)z * sC : 0);
    const int tid = threadIdx.x;
    const int lane16 = tid & 15;
    const int quad = (tid & 63) >> 4;
    const int wrow = (tid >> 6) >> 1, wcol = (tid >> 6) & 1;

    f32x4 acc[4][4] = {};

    for (int k0 = 0; k0 < K; k0 += 32) {
#pragma unroll
        for (int p = 0; p < 2; ++p) {
            int u = tid + p * 256;
            int row = u >> 2, g = u & 3;
            *(s16x8*)&As[row * 40 + g * 8] =
                *(const s16x8*)(A + (long)(m0 + row) * lda + k0 + g * 8);
        }
#pragma unroll
        for (int p = 0; p < 2; ++p) {
            int u = tid + p * 256;
            int row = u >> 2, g = u & 3;
            *(s16x8*)&Bs[row * 40 + g * 8] =
                *(const s16x8*)(B + (long)(n0 + row) * ldb + k0 + g * 8);
        }
        __syncthreads();

        s16x8 af[4], bf[4];
#pragma unroll
        for (int t = 0; t < 4; ++t) {
            af[t] = *(const s16x8*)&As[(wrow * 64 + t * 16 + lane16) * 40 + quad * 8];
            bf[t] = *(const s16x8*)&Bs[(wcol * 64 + t * 16 + lane16) * 40 + quad * 8];
        }
#pragma unroll
        for (int i2 = 0; i2 < 4; ++i2)
#pragma unroll
            for (int j = 0; j < 4; ++j)
                acc[i2][j] = __builtin_amdgcn_mfma_f32_16x16x32_bf16(af[i2], bf[j], acc[i2][j], 0, 0, 0);
        __syncthreads();
    }

#pragma unroll
    for (int i2 = 0; i2 < 4; ++i2) {
        int gm = m0 + wrow * 64 + i2 * 16 + quad * 4;
#pragma unroll
        for (int j = 0; j < 4; ++j) {
            int gn = n0 + wcol * 64 + j * 16 + lane16;
#pragma unroll
            for (int r = 0; r < 4; ++r) {
                float val = acc[i2][j][r] * outscale;
                if (OBF16) Cs[(long)(gm + r) * ldc + gn] = f2bf(val);
                else       C[(long)(gm + r) * ldc + gn] = val;
            }
        }
    }
}

// ---------------------------------------------------------------------------
// FUSED edge-softmax + PV gather. 16 lanes/dst node, XCD-swizzled blocks.
// S-row staged in LDS (round-3 structure — local optimum).
// ---------------------------------------------------------------------------
__global__ __launch_bounds__(256) void attn_pv_kernel(const short* __restrict__ S,
                                                      const int* __restrict__ ei,
                                                      const float* __restrict__ eattr,
                                                      const float* __restrict__ We,
                                                      const int* __restrict__ rp_dst,
                                                      const int* __restrict__ deg_dst,
                                                      const int* __restrict__ eid_dst,
                                                      const short* __restrict__ qkvs,
                                                      float* __restrict__ alpha,
                                                      short* __restrict__ h) {
    __shared__ float sWe[EDIM_ * 128];
    __shared__ __align__(16) short sS[16][528];   // 1KB S-row per group (+pad)
    int g = threadIdx.x >> 4;
    int lane = threadIdx.x & 15;
    int gbase = (threadIdx.x & 63) & ~15;
    int b = blockIdx.x;
    int xcd = b & 7, idx = b >> 3;
    int nb = (xcd * 8 + (idx >> 5)) * 32 + (idx & 31);
    int node = nb * 16 + g;

    {
        const short* Srow = S + (long)node * 512;
        short* Sl = sS[g];
#pragma unroll
        for (int j = 0; j < 4; ++j)
            *(s16x8*)&Sl[j * 128 + lane * 8] = *(const s16x8*)(Srow + j * 128 + lane * 8);
    }
    for (int i = threadIdx.x; i < EDIM_ * 128; i += 256) sWe[i] = We[i];
    __syncthreads();
    const short* Sl = sS[g];

    float qw[EDIM_];
    {
        s16x8 qv = *(const s16x8*)(qkvs + (long)node * 512 + lane * 8);
        float qf[8];
#pragma unroll
        for (int j = 0; j < 8; ++j) qf[j] = bf2f(qv[j]);
#pragma unroll
        for (int d = 0; d < EDIM_; ++d) {
            float p = 0.f;
#pragma unroll
            for (int j = 0; j < 8; ++j) p += qf[j] * sWe[d * 128 + lane * 8 + j];
            qw[d] = p;
        }
#pragma unroll
        for (int off = 8; off; off >>= 1)
#pragma unroll
            for (int d = 0; d < EDIM_; ++d) qw[d] += __shfl_xor(qw[d], off);
#pragma unroll
        for (int d = 0; d < EDIM_; ++d) qw[d] *= 0.08838834764831845f;
    }

    int start = rp_dst[node], cnt = deg_dst[node];
    int nch = (cnt + 15) >> 4;

    float lsum = 0.f, a5[EDIM_] = {};
    int   src_c[4] = {0, 0, 0, 0};
    float a_c[4]   = {0.f, 0.f, 0.f, 0.f};
    for (int c = 0; c < nch; ++c) {
        int t = c * 16 + lane;
        int src = 0; float wv = 0.f;
        if (t < cnt) {
            int e = eid_dst[start + t];
            src = ei[e];
            float lg = bf2f(Sl[src & 511]);
            float ea[EDIM_];
#pragma unroll
            for (int d = 0; d < EDIM_; ++d) { ea[d] = eattr[e * EDIM_ + d]; lg += ea[d] * qw[d]; }
            wv = expf(lg);
            lsum += wv;
#pragma unroll
            for (int d = 0; d < EDIM_; ++d) a5[d] += wv * ea[d];
        }
        if (c < 4) { src_c[c] = src; a_c[c] = wv; }
        else if (t < cnt) alpha[start + t] = wv;
    }
#pragma unroll
    for (int off = 8; off; off >>= 1) {
        lsum += __shfl_xor(lsum, off);
#pragma unroll
        for (int d = 0; d < EDIM_; ++d) a5[d] += __shfl_xor(a5[d], off);
    }
    float inv = (lsum > 0.f) ? 1.f / lsum : 0.f;
    float e5[EDIM_];
#pragma unroll
    for (int d = 0; d < EDIM_; ++d) e5[d] = a5[d] * inv;

    float acc[8] = {};
    for (int c = 0; c < nch; ++c) {
        int src; float a;
        if (c < 4) { src = src_c[c]; a = a_c[c]; }
        else {
            int t = c * 16 + lane;
            if (t < cnt) {
                int e = eid_dst[start + t];
                src = ei[e];
                a = alpha[start + t];
            } else { src = 0; a = 0.f; }
        }
        int m = min(16, cnt - c * 16);
        if (m == 16) {
#pragma unroll
            for (int j = 0; j < 16; ++j) {
                int   sj = __shfl(src, gbase + j);
                float aj = __shfl(a,   gbase + j);
                s16x8 v = *(const s16x8*)(qkvs + (long)sj * 512 + 256 + lane * 8);
#pragma unroll
                for (int k = 0; k < 8; ++k) acc[k] += aj * bf2f(v[k]);
            }
        } else {
            for (int j = 0; j < m; ++j) {
                int   sj = __shfl(src, gbase + j);
                float aj = __shfl(a,   gbase + j);
                s16x8 v = *(const s16x8*)(qkvs + (long)sj * 512 + 256 + lane * 8);
#pragma unroll
                for (int k = 0; k < 8; ++k) acc[k] += aj * bf2f(v[k]);
            }
        }
    }

    s16x8 sk = *(const s16x8*)(qkvs + (long)node * 512 + 384 + lane * 8);
    s16x8 o;
#pragma unroll
    for (int j = 0; j < 8; ++j) {
        float ec = 0.f;
#pragma unroll
        for (int d = 0; d < EDIM_; ++d) ec += e5[d] * sWe[d * 128 + lane * 8 + j];
        float val = acc[j] * inv + ec + bf2f(sk[j]);
        o[j] = f2bf(fmaxf(val, 0.f));
    }
    *(s16x8*)(h + (long)node * 128 + lane * 8) = o;
}

// ---------------------------------------------------------------------------
// T1 = A @ s1b computed SPARSELY over edges (src-CSR, XCD-swizzled)
// ---------------------------------------------------------------------------
__global__ __launch_bounds__(256) void t1_gather_kernel(const int* __restrict__ ei,
                                                        const int* __restrict__ rp_src,
                                                        const int* __restrict__ deg_src,
                                                        const int* __restrict__ eid_src,
                                                        const short* __restrict__ s1b,
                                                        short* __restrict__ T1s) {
    int g = threadIdx.x >> 4;
    int lane = threadIdx.x & 15;
    int gbase = (threadIdx.x & 63) & ~15;
    int b = blockIdx.x;
    int xcd = b & 7, idx = b >> 3;
    int nb = (xcd * 8 + (idx >> 5)) * 32 + (idx & 31);
    int node = nb * 16 + g;

    int start = rp_src[node], cnt = deg_src[node];
    int nch = (cnt + 15) >> 4;
    float acc[16] = {};
    for (int c = 0; c < nch; ++c) {
        int t = c * 16 + lane;
        int dst = 0;
        if (t < cnt) {
            int e = eid_src[start + t];
            dst = ei[EDGES + e];
        }
        int m = min(16, cnt - c * 16);
        if (m == 16) {
#pragma unroll
            for (int j = 0; j < 16; ++j) {
                int dj = __shfl(dst, gbase + j);
                const s16x8* p = (const s16x8*)(s1b + (long)dj * 256 + lane * 16);
                s16x8 v0 = p[0], v1 = p[1];
#pragma unroll
                for (int k = 0; k < 8; ++k) { acc[k] += bf2f(v0[k]); acc[8 + k] += bf2f(v1[k]); }
            }
        } else {
            for (int j = 0; j < m; ++j) {
                int dj = __shfl(dst, gbase + j);
                const s16x8* p = (const s16x8*)(s1b + (long)dj * 256 + lane * 16);
                s16x8 v0 = p[0], v1 = p[1];
#pragma unroll
                for (int k = 0; k < 8; ++k) { acc[k] += bf2f(v0[k]); acc[8 + k] += bf2f(v1[k]); }
            }
        }
    }
    s16x8 o0, o1;
#pragma unroll
    for (int k = 0; k < 8; ++k) { o0[k] = f2bf(acc[k]); o1[k] = f2bf(acc[8 + k]); }
    short* o = T1s + (long)node * 256 + lane * 16;
    *(s16x8*)(o)     = o0;
    *(s16x8*)(o + 8) = o1;
}

// ---------------------------------------------------------------------------
// Readout — g = gsum/128 (column sums accumulated by fused_gc3 COLSUM)
// ---------------------------------------------------------------------------
__global__ __launch_bounds__(128) void readout_kernel(const float* __restrict__ gsum,
                                                      const float* __restrict__ W_lin1,
                                                      const float* __restrict__ b_lin1,
                                                      const float* __restrict__ W_ro,
                                                      const float* __restrict__ b_ro,
                                                      float* __restrict__ out) {
    int b = blockIdx.x, t = threadIdx.x;
    __shared__ float g[128], g2[128], wred[2];
    g[t] = gsum[(long)b * 128 + t] * (1.f / (float)K2C);
    __syncthreads();
    float u = b_lin1[t];
    for (int k = 0; k < 128; ++k) u += g[k] * W_lin1[k * 128 + t];
    g2[t] = fmaxf(u, 0.f);
    __syncthreads();
    float p = g2[t] * W_ro[t];
#pragma unroll
    for (int off = 32; off; off >>= 1) p += __shfl_xor(p, off);
    if ((t & 63) == 0) wred[t >> 6] = p;
    __syncthreads();
    if (t == 0) {
        float tot = wred[0] + wred[1] + b_ro[0];
        out[b] = 1.f / (1.f + expf(-tot));
    }
}

// ---------------------------------------------------------------------------
extern "C" void kernel_launch(void* const* d_in, const int* in_sizes, int n_in,
                              void* d_out, int out_size, void* d_ws, size_t ws_size,
                              hipStream_t stream) {
    const float* x      = (const float*)d_in[0];
    const int*   ei     = (const int*)d_in[1];
    const float* eattr  = (const float*)d_in[2];
    const float* gamma  = (const float*)d_in[4];
    const float* beta   = (const float*)d_in[5];
    const float* Wq     = (const float*)d_in[6];
    const float* bq     = (const float*)d_in[7];
    const float* Wk     = (const float*)d_in[8];
    const float* bk     = (const float*)d_in[9];
    const float* Wv     = (const float*)d_in[10];
    const float* bv     = (const float*)d_in[11];
    const float* We     = (const float*)d_in[12];
    const float* Wskip  = (const float*)d_in[13];
    const float* bskip  = (const float*)d_in[14];
    const float* W_mlp1 = (const float*)d_in[15];
    const float* b_mlp1 = (const float*)d_in[16];
    const float* W2_rel = (const float*)d_in[17];
    const float* b2_rel = (const float*)d_in[18];
    const float* W2_root= (const float*)d_in[19];
    const float* W_mlp2 = (const float*)d_in[20];
    const float* b_mlp2 = (const float*)d_in[21];
    const float* W3_rel = (const float*)d_in[22];
    const float* b3_rel = (const float*)d_in[23];
    const float* W3_root= (const float*)d_in[24];
    const float* W_lin1 = (const float*)d_in[25];
    const float* b_lin1 = (const float*)d_in[26];
    const float* W_ro   = (const float*)d_in[27];
    const float* b_ro   = (const float*)d_in[28];
    float* out = (float*)d_out;

    char* w = (char*)d_ws;
    const size_t MB = 1ull << 20;
    // Workspace, lifetime-aliased (round-9 layout).
    short* qkvs = (short*)(w + 0);          // [NTOT,512] bf16 32MB (dead after step 6)
    short* S    = (short*)(w + 32 * MB);    // [NTOT,512] bf16 32MB (steps 5-6)
    short* T1s  = (short*)(w + 48 * MB);    // [NTOT,256] bf16 16MB (steps 8-9, over dead S hi)
    short* s1b  = (short*)(w + 64 * MB);    // [NTOT,256] bf16 16MB
    short* xd2  = (short*)(w + 56 * MB);    // [B,256,128] bf16 4MB
    short* s2b  = (short*)(w + 72 * MB);    // [B,256,128] bf16 4MB
    float* t2   = (float*)(w + 64 * MB);    // [B,256,128] fp32 8MB
    float* adj2 = (float*)(w + 0);          // [B,128,128] 4MB (raw)
    float* xp2  = (float*)(w + 4 * MB);     // [B,128,128] 4MB
    float* adj1 = (float*)(w + 80 * MB);    // [B,256,256] 16MB (raw)
    float* xp1  = (float*)(w + 96 * MB);    // [B,256,128] 8MB
    float* alpha= (float*)(w + 97 * MB);    // [EDGES] fp32 2MB (overflow spill; dead
                                            //  after attn_pv, before xp1 written)
    short* h    = (short*)(w + 112 * MB);   // [NTOT,128] bf16 8MB (steps 6-pool1)
    char* misc  = w + 104 * MB;
    short* W4b    = (short*)(misc + 0x00000);   // [128,512] bf16 (pre-packed)
    float* bias4  = (float*)(misc + 0x40000);
    float* scale  = (float*)(misc + 0x41400);
    float* shift  = (float*)(misc + 0x41600);
    float* rowsum1= (float*)(misc + 0x42000);   // [B,256] fp32 64KB (zeroed)
    float* rowsum2= (float*)(misc + 0x52000);   // [B,128] fp32 32KB (zeroed)
    int* deg_src  = (int*)(misc + 0x60000);
    int* deg_dst  = (int*)(misc + 0x80000);
    int* rp_src   = (int*)(misc + 0xA0000);
    int* rp_dst   = (int*)(misc + 0xC0000);
    int* eid_src  = (int*)(misc + 0x120000);
    int* eid_dst  = (int*)(misc + 0x320000);
    float* psum   = (float*)(misc + 0x520000);
    float* psq    = (float*)(misc + 0x540000);
    float* gsum   = (float*)(misc + 0x560000);  // [B,128] fp32 32KB (zeroed in fin)

    // Zero rowsum1 + rowsum2 only.
    hipMemsetAsync(misc + 0x42000, 0, 0x18000, stream);

    // 1. MERGED: BN stats + weight pack (W4 packed as bf16)
    prep_kernel<<<512, 256, 0, stream>>>(x, psum, psq,
                                         Wq, Wk, Wv, Wskip, bq, bk, bv, bskip,
                                         W4b, bias4);

    // 2. BN finalize + gsum zero
    fin_kernel<<<1, 1024, 0, stream>>>(psum, psq, gamma, beta, scale, shift, gsum);

    // 3. MERGED: CSR build FIRST (long-pole blocks 0..127 start at t=0,
    //    hide under GEMM) ∥ qkvs GEMM (blocks 128..1151)
    qkvs_csr_kernel<<<1152, 256, 0, stream>>>(x, W4b, bias4, qkvs, scale, shift,
                                              ei, rp_src, deg_src, eid_src,
                                              rp_dst, deg_dst, eid_dst);

    // 4. S(bf16) = (Q @ K^T) / sqrt(H) per graph (dense MFMA, XCD-aligned)
    bgemm<true><<<dim3(4, 4, BGRAPH), 256, 0, stream>>>(
        qkvs + 0, qkvs + 128, S, 0.08838834764831845f,
        NNODE, NNODE, 128, 512, 512, 512,
        (long)NNODE * 512, (long)NNODE * 512, (long)NNODE * NNODE);

    // 5. FUSED edge-softmax + PV gather -> h(bf16)
    attn_pv_kernel<<<NTOT / 16, 256, 0, stream>>>(
        S, ei, eattr, We, rp_dst, deg_dst, eid_dst, qkvs, alpha, h);

    // 6. s1b(bf16) = softmax_row(h @ W_mlp1 + b)
    mlp_softmax_kernel<K1C><<<NTOT / 64, 256, 0, stream>>>(h, W_mlp1, b_mlp1, s1b);

    // 7. T1(bf16) = A @ s1b via sparse edge gather (src-CSR)
    t1_gather_kernel<<<NTOT / 16, 256, 0, stream>>>(
        ei, rp_src, deg_src, eid_src, s1b, T1s);

    // 8. MERGED pool1: xp1 = s1b^T h ∥ adj1(raw) = s1b^T T1s (+ROWSUM)
    pool1_kernel<<<768, 256, 0, stream>>>(s1b, h, T1s, xp1, adj1, rowsum1);

    // 9. FUSED GraphConv2: xd2 = relu([adjN1@xp1 | xp1]@[W2_rel;W2_root]+b)
    fused_gc_kernel<K1C, true, true, false><<<dim3(4, BGRAPH), 256, 0, stream>>>(
        adj1, rowsum1, xp1, W2_rel, b2_rel, W2_root, xd2);

    // 10. s2b(bf16) = softmax_row(xd2 @ W_mlp2 + b)
    mlp_softmax_kernel<K2C><<<(BGRAPH * K1C) / 64, 256, 0, stream>>>(xd2, W_mlp2, b_mlp2, s2b);

    // 11. MERGED pool2: t2 = adjN1@s2b (ANORM) ∥ xp2 = s2b^T xd2
    pool2_kernel<<<768, 256, 0, stream>>>(adj1, rowsum1, s2b, xd2, t2, xp2);

    // 12. adj2(raw) = s2b^T t2 (+ROWSUM -> rowsum2)
    mgemm<64, true, false, false, true, false, false, false, false, false, true, false>
        <<<dim3(2, 2, BGRAPH), 256, 0, stream>>>(
        s2b, t2, nullptr, nullptr, 0, nullptr, adj2, nullptr, rowsum2,
        K2C, K2C, K1C, K2C, K2C, K2C,
        (long)K1C * K2C, (long)K1C * K2C, (long)K2C * K2C);

    // 13. FUSED GraphConv3 + COLSUM -> gsum (xd3 never materialized)
    fused_gc_kernel<K2C, false, false, true><<<dim3(2, BGRAPH), 256, 0, stream>>>(
        adj2, rowsum2, xp2, W3_rel, b3_rel, W3_root, gsum);

    // 14. Readout from gsum
    readout_kernel<<<BGRAPH, 128, 0, stream>>>(gsum, W_lin1, b_lin1, W_ro, b_ro, out);

    (void)in_sizes; (void)n_in; (void)out_size; (void)ws_size;
}

// Round 16
// 410.043 us; speedup vs baseline: 1.0380x; 1.0221x over previous
//
#include <hip/hip_runtime.h>
#include <math.h>

// Problem constants
#define BGRAPH 64
#define NNODE  512
#define NTOT   32768        // BGRAPH*NNODE
#define CIN    128
#define HDIM   128
#define EDIM_  5
#define EDGES  524288
#define EPG    8192         // edges per graph
#define K1C    256
#define K2C    128

using f32x4 = __attribute__((ext_vector_type(4))) float;
using s16x8 = __attribute__((ext_vector_type(8))) short;

__device__ __forceinline__ short f2bf(float f) {
    union { float f; unsigned u; } v; v.f = f;
    unsigned r = v.u + 0x7fffu + ((v.u >> 16) & 1u);   // RNE
    return (short)(r >> 16);
}
__device__ __forceinline__ float bf2f(short s) {
    union { unsigned u; float f; } v; v.u = ((unsigned)(unsigned short)s) << 16;
    return v.f;
}

// ---------------------------------------------------------------------------
// MERGED prep: BatchNorm stats (blocks 0..255) + weight pack (256..511).
// (Edge histogram removed — CSR built per-graph in LDS by qkvs_csr.)
// ---------------------------------------------------------------------------
__global__ __launch_bounds__(256) void prep_kernel(const float* __restrict__ x,
                                                   float* __restrict__ psum,
                                                   float* __restrict__ psq,
                                                   const float* __restrict__ Wq, const float* __restrict__ Wk,
                                                   const float* __restrict__ Wv, const float* __restrict__ Ws,
                                                   const float* __restrict__ bq, const float* __restrict__ bk,
                                                   const float* __restrict__ bv, const float* __restrict__ bs,
                                                   float* __restrict__ W4, float* __restrict__ bias4) {
    __shared__ float ss[128], sq[128];
    int tid = threadIdx.x, bid = blockIdx.x;
    if (bid < 256) {
        long idx0 = (long)bid * 256 + tid;
        float4 s = {0.f, 0.f, 0.f, 0.f}, q = {0.f, 0.f, 0.f, 0.f};
#pragma unroll
        for (int it = 0; it < 16; ++it) {
            float4 v = *(const float4*)(x + (idx0 + (long)it * 65536) * 4);
            s.x += v.x; s.y += v.y; s.z += v.z; s.w += v.w;
            q.x += v.x * v.x; q.y += v.y * v.y; q.z += v.z * v.z; q.w += v.w * v.w;
        }
        if (tid < 128) { ss[tid] = 0.f; sq[tid] = 0.f; }
        __syncthreads();
        int c0 = (tid & 31) * 4;
        atomicAdd(&ss[c0 + 0], s.x); atomicAdd(&ss[c0 + 1], s.y);
        atomicAdd(&ss[c0 + 2], s.z); atomicAdd(&ss[c0 + 3], s.w);
        atomicAdd(&sq[c0 + 0], q.x); atomicAdd(&sq[c0 + 1], q.y);
        atomicAdd(&sq[c0 + 2], q.z); atomicAdd(&sq[c0 + 3], q.w);
        __syncthreads();
        if (tid < 128) {
            psum[bid * 128 + tid] = ss[tid];
            psq[bid * 128 + tid]  = sq[tid];
        }
    } else {
        int i = (bid - 256) * 256 + tid;
        if (i < 128 * 512) {
            int k = i / 512, j = i % 512;
            float v;
            if (j < 128)      v = Wq[k * 128 + j];
            else if (j < 256) v = Wk[k * 128 + (j - 128)];
            else if (j < 384) v = Wv[k * 128 + (j - 256)];
            else              v = Ws[k * 128 + (j - 384)];
            W4[i] = v;
        }
        if (i < 512) {
            float v;
            if (i < 128)      v = bq[i];
            else if (i < 256) v = bk[i - 128];
            else if (i < 384) v = bv[i - 256];
            else              v = bs[i - 384];
            bias4[i] = v;
        }
    }
}

// ---------------------------------------------------------------------------
// BatchNorm finalize + gsum zero (1 block).
// ---------------------------------------------------------------------------
__global__ __launch_bounds__(1024) void fin_kernel(const float* __restrict__ psum,
                                                   const float* __restrict__ psq,
                                                   const float* __restrict__ gamma,
                                                   const float* __restrict__ beta,
                                                   float* __restrict__ scale,
                                                   float* __restrict__ shift,
                                                   float* __restrict__ gsum) {
    int tid = threadIdx.x;
    if (tid < 128) {
        int c = tid;
        float s = 0.f, q = 0.f;
        for (int b = 0; b < 256; ++b) { s += psum[b * 128 + c]; q += psq[b * 128 + c]; }
        float mu  = s / (float)NTOT;
        float var = q / (float)NTOT - mu * mu;
        float rstd = rsqrtf(var + 1e-5f);
        float sc = gamma[c] * rstd;
        scale[c] = sc;
        shift[c] = beta[c] - mu * sc;
    }
    for (int i = tid; i < BGRAPH * 128; i += 1024) gsum[i] = 0.f;
}

// ---------------------------------------------------------------------------
// BF16 MFMA GEMM body (device), tile TILE x TILE (128 or 64), BK=32.
//   AU8: A uint8. ATRBF16: TRANS_A bf16 A. ABF16: !TRANS_A bf16 A.
//   BBF16: B bf16. OBF16: bf16 out. DUAL: concat-K second source.
//   ANORM: A is raw pooled adjacency; apply (r==c?0:v*dinv[r]*dinv[c]) at
//   staging; dvl (LDS) filled from `scale` = rowsum buffer (stride lda).
//   ROWSUM: epilogue accumulates per-row sums of C (diag excluded) into
//   (float*)shift via deterministic shfl reduce + commutative atomics.
// Block coords passed explicitly so merged wrappers can remap blocks.
// ---------------------------------------------------------------------------
template <int TILE, bool TRANS_A, bool AFFINE, bool ANORM, bool ROWSUM, bool RELU,
          bool DUAL, bool OBF16, bool AU8, bool BBF16, bool ATRBF16, bool ABF16>
__device__ __forceinline__ void mgemm_body(short* As, short* Bs, float* dvl,
                                           const void* __restrict__ Av,
                                           const void* __restrict__ Bv,
                                           const void* __restrict__ A2v,
                                           const void* __restrict__ B2v,
                                           int Ksplit,
                                           const float* __restrict__ bias,
                                           void* __restrict__ Cv,
                                           const float* __restrict__ scale,
                                           const float* __restrict__ shift,
                                           int M, int Nc, int K,
                                           int lda, int ldb, int ldc,
                                           long sA, long sB, long sC,
                                           int bx, int by, int bz) {
    constexpr int ASZ = AU8 ? 1 : ((ATRBF16 || ABF16) ? 2 : 4);
    constexpr int BSZ = BBF16 ? 2 : 4;
    const char* Abase = (const char*)Av + (long)bz * sA * ASZ;
    const char* Bbase = (const char*)Bv + (long)bz * sB * BSZ;
    float* C = (float*)Cv + (OBF16 ? 0 : (long)bz * sC);
    short* Cs = (short*)Cv + (OBF16 ? (long)bz * sC : 0);
    const int m0 = by * TILE, n0 = bx * TILE;
    const int tid = threadIdx.x;
    const int lane16 = tid & 15;
    const int quad = (tid & 63) >> 4;
    const int wrow = (tid >> 6) >> 1, wcol = (tid >> 6) & 1;
    constexpr int WT = TILE / 32;

    if (ANORM) {
        for (int i = tid; i < K; i += 256)
            dvl[i] = 1.f / (sqrtf(scale[(long)bz * lda + i]) + 1e-15f);
        __syncthreads();
    }

    f32x4 acc[WT][WT] = {};

    for (int k0 = 0; k0 < K; k0 += 32) {
        const char* Au = Abase; const char* Bu = Bbase; int ku = k0;
        if (DUAL && k0 >= Ksplit) { Au = (const char*)A2v; Bu = (const char*)B2v; ku = k0 - Ksplit; }

        if (!TRANS_A) {
#pragma unroll
            for (int p = 0; p < TILE / 32; ++p) {
                int idx = tid + p * 256;
                int row = idx >> 3, c4 = idx & 7;
                short4 o;
                if (AU8) {
                    unsigned u = *(const unsigned*)((const unsigned char*)Au +
                                                    (long)(m0 + row) * lda + ku + c4 * 4);
                    o = make_short4(f2bf((float)(u & 255u)), f2bf((float)((u >> 8) & 255u)),
                                    f2bf((float)((u >> 16) & 255u)), f2bf((float)((u >> 24) & 255u)));
                } else if (ABF16) {
                    o = *(const short4*)((const short*)Au + (long)(m0 + row) * lda + ku + c4 * 4);
                } else {
                    float4 v = *(const float4*)((const float*)Au + (long)(m0 + row) * lda + ku + c4 * 4);
                    if (AFFINE) {
                        int k = ku + c4 * 4;
                        v.x = v.x * scale[k] + shift[k];
                        v.y = v.y * scale[k + 1] + shift[k + 1];
                        v.z = v.z * scale[k + 2] + shift[k + 2];
                        v.w = v.w * scale[k + 3] + shift[k + 3];
                    }
                    if (ANORM) {
                        int k = ku + c4 * 4;
                        int grow = m0 + row;
                        float dr = dvl[grow];
                        v.x = (grow == k + 0) ? 0.f : v.x * dr * dvl[k + 0];
                        v.y = (grow == k + 1) ? 0.f : v.y * dr * dvl[k + 1];
                        v.z = (grow == k + 2) ? 0.f : v.z * dr * dvl[k + 2];
                        v.w = (grow == k + 3) ? 0.f : v.w * dr * dvl[k + 3];
                    }
                    o = make_short4(f2bf(v.x), f2bf(v.y), f2bf(v.z), f2bf(v.w));
                }
                *(short4*)&As[row * 40 + c4 * 4] = o;
            }
        } else {
            if (TILE == 128 || tid < 128) {
                int c4 = tid >> 3, g = tid & 7;        // row-group slow, k-group fast
                short* d = &As[(c4 * 4) * 40 + g * 4];
                if (ATRBF16) {
                    const short* src = (const short*)Au + (long)(ku + g * 4) * lda + m0 + c4 * 4;
                    short4 r0 = *(const short4*)(src);
                    short4 r1 = *(const short4*)(src + lda);
                    short4 r2 = *(const short4*)(src + 2 * lda);
                    short4 r3 = *(const short4*)(src + 3 * lda);
                    *(short4*)(d + 0 * 40) = make_short4(r0.x, r1.x, r2.x, r3.x);
                    *(short4*)(d + 1 * 40) = make_short4(r0.y, r1.y, r2.y, r3.y);
                    *(short4*)(d + 2 * 40) = make_short4(r0.z, r1.z, r2.z, r3.z);
                    *(short4*)(d + 3 * 40) = make_short4(r0.w, r1.w, r2.w, r3.w);
                } else {
                    const float* src = (const float*)Au + (long)(ku + g * 4) * lda + m0 + c4 * 4;
                    float4 r0 = *(const float4*)(src);
                    float4 r1 = *(const float4*)(src + lda);
                    float4 r2 = *(const float4*)(src + 2 * lda);
                    float4 r3 = *(const float4*)(src + 3 * lda);
                    *(short4*)(d + 0 * 40) = make_short4(f2bf(r0.x), f2bf(r1.x), f2bf(r2.x), f2bf(r3.x));
                    *(short4*)(d + 1 * 40) = make_short4(f2bf(r0.y), f2bf(r1.y), f2bf(r2.y), f2bf(r3.y));
                    *(short4*)(d + 2 * 40) = make_short4(f2bf(r0.z), f2bf(r1.z), f2bf(r2.z), f2bf(r3.z));
                    *(short4*)(d + 3 * 40) = make_short4(f2bf(r0.w), f2bf(r1.w), f2bf(r2.w), f2bf(r3.w));
                }
            }
        }
        if (TILE == 128 || tid < 128) {
            int c4 = tid >> 3, g = tid & 7;            // n-group slow, k-group fast
            short* d = &Bs[(c4 * 4) * 40 + g * 4];
            if (BBF16) {
                const short* src = (const short*)Bu + (long)(ku + g * 4) * ldb + n0 + c4 * 4;
                short4 r0 = *(const short4*)(src);
                short4 r1 = *(const short4*)(src + ldb);
                short4 r2 = *(const short4*)(src + 2 * ldb);
                short4 r3 = *(const short4*)(src + 3 * ldb);
                *(short4*)(d + 0 * 40) = make_short4(r0.x, r1.x, r2.x, r3.x);
                *(short4*)(d + 1 * 40) = make_short4(r0.y, r1.y, r2.y, r3.y);
                *(short4*)(d + 2 * 40) = make_short4(r0.z, r1.z, r2.z, r3.z);
                *(short4*)(d + 3 * 40) = make_short4(r0.w, r1.w, r2.w, r3.w);
            } else {
                const float* src = (const float*)Bu + (long)(ku + g * 4) * ldb + n0 + c4 * 4;
                float4 r0 = *(const float4*)(src);
                float4 r1 = *(const float4*)(src + ldb);
                float4 r2 = *(const float4*)(src + 2 * ldb);
                float4 r3 = *(const float4*)(src + 3 * ldb);
                *(short4*)(d + 0 * 40) = make_short4(f2bf(r0.x), f2bf(r1.x), f2bf(r2.x), f2bf(r3.x));
                *(short4*)(d + 1 * 40) = make_short4(f2bf(r0.y), f2bf(r1.y), f2bf(r2.y), f2bf(r3.y));
                *(short4*)(d + 2 * 40) = make_short4(f2bf(r0.z), f2bf(r1.z), f2bf(r2.z), f2bf(r3.z));
                *(short4*)(d + 3 * 40) = make_short4(f2bf(r0.w), f2bf(r1.w), f2bf(r2.w), f2bf(r3.w));
            }
        }
        __syncthreads();

        s16x8 af[WT], bf[WT];
#pragma unroll
        for (int t = 0; t < WT; ++t) {
            af[t] = *(const s16x8*)&As[(wrow * (TILE / 2) + t * 16 + lane16) * 40 + quad * 8];
            bf[t] = *(const s16x8*)&Bs[(wcol * (TILE / 2) + t * 16 + lane16) * 40 + quad * 8];
        }
#pragma unroll
        for (int i = 0; i < WT; ++i)
#pragma unroll
            for (int j = 0; j < WT; ++j)
                acc[i][j] = __builtin_amdgcn_mfma_f32_16x16x32_bf16(af[i], bf[j], acc[i][j], 0, 0, 0);
        __syncthreads();
    }

#pragma unroll
    for (int i = 0; i < WT; ++i) {
        int gm = m0 + wrow * (TILE / 2) + i * 16 + quad * 4;
#pragma unroll
        for (int j = 0; j < WT; ++j) {
            int gn = n0 + wcol * (TILE / 2) + j * 16 + lane16;
            float bv = bias ? bias[gn] : 0.f;
#pragma unroll
            for (int r = 0; r < 4; ++r) {
                float val = acc[i][j][r] + bv;
                if (RELU) val = fmaxf(val, 0.f);
                if (OBF16) Cs[(long)(gm + r) * ldc + gn] = f2bf(val);
                else       C[(long)(gm + r) * ldc + gn] = val;
            }
        }
    }

    if (ROWSUM) {
        float* rlA = (float*)As;
        float* rlB = (float*)Bs;
#pragma unroll
        for (int i = 0; i < WT; ++i) {
#pragma unroll
            for (int r = 0; r < 4; ++r) {
                int gm = m0 + wrow * (TILE / 2) + i * 16 + quad * 4 + r;
                float p = 0.f;
#pragma unroll
                for (int j = 0; j < WT; ++j) {
                    int gn = n0 + wcol * (TILE / 2) + j * 16 + lane16;
                    p += (gn == gm) ? 0.f : acc[i][j][r];
                }
#pragma unroll
                for (int off = 1; off < 16; off <<= 1) p += __shfl_xor(p, off);
                if (lane16 == 0) {
                    int rl = wrow * (TILE / 2) + i * 16 + quad * 4 + r;
                    (wcol ? rlB : rlA)[rl] = p;
                }
            }
        }
        __syncthreads();
        float* rout = (float*)shift;
        for (int t = tid; t < TILE; t += 256)
            atomicAdd(&rout[(long)bz * M + m0 + t], rlA[t] + rlB[t]);
    }
}

// Standalone wrapper (used for adj2)
template <int TILE, bool TRANS_A, bool AFFINE, bool ANORM, bool ROWSUM, bool RELU,
          bool DUAL, bool OBF16, bool AU8, bool BBF16, bool ATRBF16, bool ABF16>
__global__ __launch_bounds__(256) void mgemm(const void* __restrict__ Av,
                                             const void* __restrict__ Bv,
                                             const void* __restrict__ A2v,
                                             const void* __restrict__ B2v,
                                             int Ksplit,
                                             const float* __restrict__ bias,
                                             void* __restrict__ Cv,
                                             const float* __restrict__ scale,
                                             const float* __restrict__ shift,
                                             int M, int Nc, int K,
                                             int lda, int ldb, int ldc,
                                             long sA, long sB, long sC) {
    __shared__ __align__(16) short As[TILE * 40];
    __shared__ __align__(16) short Bs[TILE * 40];
    __shared__ float dvl[ANORM ? 256 : 1];
    mgemm_body<TILE, TRANS_A, AFFINE, ANORM, ROWSUM, RELU, DUAL, OBF16, AU8, BBF16, ATRBF16, ABF16>(
        As, Bs, dvl, Av, Bv, A2v, B2v, Ksplit, bias, Cv, scale, shift,
        M, Nc, K, lda, ldb, ldc, sA, sB, sC,
        blockIdx.x, blockIdx.y, blockIdx.z);
}

// ---------------------------------------------------------------------------
// Per-graph LDS CSR build (one block per graph+direction): histogram via LDS
// atomics, 512-entry LDS scan, scatter into LDS eid buffer, one coalesced
// 32KB write. NO global atomics; eid written exactly once.
// smemInt layout: cnt[512] | part[256] | eidl[8192]  (35840 B)
// ---------------------------------------------------------------------------
__device__ __forceinline__ void csr_build_graph(int* smemInt,
                                                const int* __restrict__ ei_dir,
                                                int gnode0, int gedge0,
                                                int* __restrict__ rp,
                                                int* __restrict__ deg,
                                                int* __restrict__ eid) {
    int* cnt  = smemInt;
    int* part = smemInt + 512;
    int* eidl = smemInt + 768;
    int tid = threadIdx.x;
    cnt[tid] = 0; cnt[tid + 256] = 0;
    __syncthreads();
    // histogram
    for (int k = 0; k < EPG / 256; ++k) {
        int e = gedge0 + k * 256 + tid;
        atomicAdd(&cnt[ei_dir[e] & 511], 1);
    }
    __syncthreads();
    // exclusive scan over 512 (thread t owns counters 2t, 2t+1)
    int c0 = cnt[2 * tid], c1 = cnt[2 * tid + 1];
    part[tid] = c0 + c1;
    __syncthreads();
    for (int off = 1; off < 256; off <<= 1) {
        int v = part[tid];
        int add = (tid >= off) ? part[tid - off] : 0;
        __syncthreads();
        part[tid] = v + add;
        __syncthreads();
    }
    int excl = (tid == 0) ? 0 : part[tid - 1];
    rp[gnode0 + 2 * tid]      = gedge0 + excl;
    rp[gnode0 + 2 * tid + 1]  = gedge0 + excl + c0;
    deg[gnode0 + 2 * tid]     = c0;
    deg[gnode0 + 2 * tid + 1] = c1;
    cnt[2 * tid]     = excl;        // becomes local cursor
    cnt[2 * tid + 1] = excl + c0;
    __syncthreads();
    // scatter into LDS
    for (int k = 0; k < EPG / 256; ++k) {
        int e = gedge0 + k * 256 + tid;
        int pos = atomicAdd(&cnt[ei_dir[e] & 511], 1);
        eidl[pos] = e;
    }
    __syncthreads();
    // coalesced write-out
    for (int k = 0; k < EPG / 256; ++k)
        eid[gedge0 + k * 256 + tid] = eidl[k * 256 + tid];
}

// ---------------------------------------------------------------------------
// MERGED: qkvs GEMM (blocks 0..1023) + per-graph LDS CSR build (1024..1151:
// 64 graphs x {src,dst}). Both depend only on prep/fin. LDS unioned (36KB).
// ---------------------------------------------------------------------------
__global__ __launch_bounds__(256) void qkvs_csr_kernel(const float* __restrict__ x,
                                                       const float* __restrict__ W4,
                                                       const float* __restrict__ bias4,
                                                       short* __restrict__ qkvs,
                                                       const float* __restrict__ scale,
                                                       const float* __restrict__ shift,
                                                       const int* __restrict__ ei,
                                                       int* __restrict__ rp_src,
                                                       int* __restrict__ deg_src,
                                                       int* __restrict__ eid_src,
                                                       int* __restrict__ rp_dst,
                                                       int* __restrict__ deg_dst,
                                                       int* __restrict__ eid_dst) {
    __shared__ __align__(16) char smem[35840];
    int b = blockIdx.x;
    if (b < 1024) {
        short* As = (short*)smem;
        short* Bs = (short*)(smem + 10240);
        mgemm_body<128, false, true, false, false, false, false, true, false, false, false, false>(
            As, Bs, nullptr, x, W4, nullptr, nullptr, 0, bias4, qkvs, scale, shift,
            NTOT, 512, 128, 128, 512, 512, 0, 0, 0,
            b & 3, b >> 2, 0);
    } else {
        int j = b - 1024;                    // [0,128): graph = j>>1, dir = j&1
        int g = j >> 1;
        if (j & 1)
            csr_build_graph((int*)smem, ei + EDGES, g * NNODE, g * EPG,
                            rp_dst, deg_dst, eid_dst);
        else
            csr_build_graph((int*)smem, ei, g * NNODE, g * EPG,
                            rp_src, deg_src, eid_src);
    }
}

// ---------------------------------------------------------------------------
// MERGED pool1: xp1 = s1b^T h (blocks 0..511) ∥ adj1(raw)=s1b^T T1s + ROWSUM
// (blocks 512..767). Outputs disjoint (h at 112MB; adj1 at 80MB).
// ---------------------------------------------------------------------------
__global__ __launch_bounds__(256) void pool1_kernel(const short* __restrict__ s1b,
                                                    const short* __restrict__ h,
                                                    const short* __restrict__ T1s,
                                                    float* __restrict__ xp1,
                                                    float* __restrict__ adj1,
                                                    float* __restrict__ rowsum1) {
    __shared__ __align__(16) short As[128 * 40];
    __shared__ __align__(16) short Bs[128 * 40];
    int b = blockIdx.x;
    if (b < 512) {
        mgemm_body<64, true, false, false, false, false, false, false, false, true, true, false>(
            As, Bs, nullptr, s1b, h, nullptr, nullptr, 0, nullptr, xp1, nullptr, nullptr,
            K1C, 128, NNODE, K1C, 128, 128,
            (long)NNODE * K1C, (long)NNODE * 128, (long)K1C * 128,
            b & 1, (b >> 1) & 3, b >> 3);
    } else {
        int j = b - 512;
        mgemm_body<128, true, false, false, true, false, false, false, false, true, true, false>(
            As, Bs, nullptr, s1b, T1s, nullptr, nullptr, 0, nullptr, adj1, nullptr, rowsum1,
            K1C, K1C, NNODE, K1C, K1C, K1C,
            (long)NNODE * K1C, (long)NNODE * K1C, (long)K1C * K1C,
            j & 1, (j >> 1) & 1, j >> 2);
    }
}

// ---------------------------------------------------------------------------
// MERGED pool2: t2 = adjN1@s2b (ANORM, blocks 0..511) ∥ xp2 = s2b^T xd2
// (blocks 512..767). Outputs disjoint (t2@64MB, xp2@4MB).
// ---------------------------------------------------------------------------
__global__ __launch_bounds__(256) void pool2_kernel(const float* __restrict__ adj1,
                                                    const float* __restrict__ rowsum1,
                                                    const short* __restrict__ s2b,
                                                    const short* __restrict__ xd2,
                                                    float* __restrict__ t2,
                                                    float* __restrict__ xp2) {
    __shared__ __align__(16) short As[64 * 40];
    __shared__ __align__(16) short Bs[64 * 40];
    __shared__ float dvl[256];
    int b = blockIdx.x;
    if (b < 512) {
        mgemm_body<64, false, false, true, false, false, false, false, false, true, false, false>(
            As, Bs, dvl, adj1, s2b, nullptr, nullptr, 0, nullptr, t2, rowsum1, nullptr,
            K1C, K2C, K1C, K1C, K2C, K2C,
            (long)K1C * K1C, (long)K1C * K2C, (long)K1C * K2C,
            b & 1, (b >> 1) & 3, b >> 3);
    } else {
        int j = b - 512;
        mgemm_body<64, true, false, false, false, false, false, false, false, true, true, false>(
            As, Bs, nullptr, s2b, xd2, nullptr, nullptr, 0, nullptr, xp2, nullptr, nullptr,
            K2C, 128, K1C, K2C, 128, 128,
            (long)K1C * K2C, (long)K1C * 128, (long)K2C * 128,
            j & 1, (j >> 1) & 1, j >> 2);
    }
}

// ---------------------------------------------------------------------------
// FUSED DenseGraphConv: Out = act( adjN@xp @ Wrel + xp @ Wroot + b )
// adjN normalized on the fly from raw adj + rowsum (dinv staged in LDS).
// COLSUM: instead of storing Out, accumulate per-graph column sums (bias
// included) into (float*)Outv = gsum[B][128] — feeds the readout mean.
// ---------------------------------------------------------------------------
template <int KADJ, bool RELU, bool OBF16, bool COLSUM>
__global__ __launch_bounds__(256) void fused_gc_kernel(const float* __restrict__ adj,
                                                       const float* __restrict__ rowsum,
                                                       const float* __restrict__ xp,
                                                       const float* __restrict__ Wrel,
                                                       const float* __restrict__ brel,
                                                       const float* __restrict__ Wroot,
                                                       void* __restrict__ Outv) {
    __shared__ __align__(16) short As[64 * 40];
    __shared__ __align__(16) short Bs[128 * 40];
    __shared__ __align__(16) short Tl[64][136];
    __shared__ float dvl[KADJ];
    __shared__ float cs[COLSUM ? 128 : 1];
    const int z = blockIdx.y;
    const int m0 = blockIdx.x * 64;
    const int tid = threadIdx.x;
    const int lane16 = tid & 15;
    const int quad = (tid & 63) >> 4;
    const int wrow = (tid >> 6) >> 1, wcol = (tid >> 6) & 1;
    const float* adjz = adj + (long)z * KADJ * KADJ;
    const float* xpz  = xp + (long)z * KADJ * 128;

    for (int i = tid; i < KADJ; i += 256)
        dvl[i] = 1.f / (sqrtf(rowsum[(long)z * KADJ + i]) + 1e-15f);
    if (COLSUM) for (int i = tid; i < 128; i += 256) cs[i] = 0.f;
    __syncthreads();

    // ---- phase 1: T[64][128] = adjN[m0..m0+64) @ xp ----
    f32x4 acc[2][4] = {};
    for (int k0 = 0; k0 < KADJ; k0 += 32) {
#pragma unroll
        for (int p = 0; p < 2; ++p) {
            int idx = tid + p * 256;
            int row = idx >> 3, c4 = idx & 7;
            int grow = m0 + row, k = k0 + c4 * 4;
            float4 v = *(const float4*)(adjz + (long)grow * KADJ + k);
            float dr = dvl[grow];
            v.x = (grow == k + 0) ? 0.f : v.x * dr * dvl[k + 0];
            v.y = (grow == k + 1) ? 0.f : v.y * dr * dvl[k + 1];
            v.z = (grow == k + 2) ? 0.f : v.z * dr * dvl[k + 2];
            v.w = (grow == k + 3) ? 0.f : v.w * dr * dvl[k + 3];
            *(short4*)&As[row * 40 + c4 * 4] =
                make_short4(f2bf(v.x), f2bf(v.y), f2bf(v.z), f2bf(v.w));
        }
        {
            int c4 = tid >> 3, g = tid & 7;
            short* d = &Bs[(c4 * 4) * 40 + g * 4];
            const float* src = xpz + (long)(k0 + g * 4) * 128 + c4 * 4;
            float4 r0 = *(const float4*)(src);
            float4 r1 = *(const float4*)(src + 128);
            float4 r2 = *(const float4*)(src + 256);
            float4 r3 = *(const float4*)(src + 384);
            *(short4*)(d + 0 * 40) = make_short4(f2bf(r0.x), f2bf(r1.x), f2bf(r2.x), f2bf(r3.x));
            *(short4*)(d + 1 * 40) = make_short4(f2bf(r0.y), f2bf(r1.y), f2bf(r2.y), f2bf(r3.y));
            *(short4*)(d + 2 * 40) = make_short4(f2bf(r0.z), f2bf(r1.z), f2bf(r2.z), f2bf(r3.z));
            *(short4*)(d + 3 * 40) = make_short4(f2bf(r0.w), f2bf(r1.w), f2bf(r2.w), f2bf(r3.w));
        }
        __syncthreads();
        s16x8 af[2], bf[4];
#pragma unroll
        for (int t = 0; t < 2; ++t)
            af[t] = *(const s16x8*)&As[(wrow * 32 + t * 16 + lane16) * 40 + quad * 8];
#pragma unroll
        for (int j = 0; j < 4; ++j)
            bf[j] = *(const s16x8*)&Bs[(wcol * 64 + j * 16 + lane16) * 40 + quad * 8];
#pragma unroll
        for (int t = 0; t < 2; ++t)
#pragma unroll
            for (int j = 0; j < 4; ++j)
                acc[t][j] = __builtin_amdgcn_mfma_f32_16x16x32_bf16(af[t], bf[j], acc[t][j], 0, 0, 0);
        __syncthreads();
    }
#pragma unroll
    for (int t = 0; t < 2; ++t)
#pragma unroll
        for (int j = 0; j < 4; ++j)
#pragma unroll
            for (int r = 0; r < 4; ++r)
                Tl[wrow * 32 + t * 16 + quad * 4 + r][wcol * 64 + j * 16 + lane16] =
                    f2bf(acc[t][j][r]);
    __syncthreads();

    // ---- phase 2: Out = [T | xp_rows] @ [Wrel; Wroot] + b ----
    f32x4 acc2[2][4] = {};
    for (int k0 = 0; k0 < 256; k0 += 32) {
        const bool useXp = (k0 >= 128);
        const float* Wsrc = useXp ? (Wroot + (long)(k0 - 128) * 128)
                                  : (Wrel + (long)k0 * 128);
        {
            int c4 = tid >> 3, g = tid & 7;
            short* d = &Bs[(c4 * 4) * 40 + g * 4];
            const float* src = Wsrc + (long)(g * 4) * 128 + c4 * 4;
            float4 r0 = *(const float4*)(src);
            float4 r1 = *(const float4*)(src + 128);
            float4 r2 = *(const float4*)(src + 256);
            float4 r3 = *(const float4*)(src + 384);
            *(short4*)(d + 0 * 40) = make_short4(f2bf(r0.x), f2bf(r1.x), f2bf(r2.x), f2bf(r3.x));
            *(short4*)(d + 1 * 40) = make_short4(f2bf(r0.y), f2bf(r1.y), f2bf(r2.y), f2bf(r3.y));
            *(short4*)(d + 2 * 40) = make_short4(f2bf(r0.z), f2bf(r1.z), f2bf(r2.z), f2bf(r3.z));
            *(short4*)(d + 3 * 40) = make_short4(f2bf(r0.w), f2bf(r1.w), f2bf(r2.w), f2bf(r3.w));
        }
        if (useXp) {
#pragma unroll
            for (int p = 0; p < 2; ++p) {
                int idx = tid + p * 256;
                int row = idx >> 3, c4 = idx & 7;
                float4 v = *(const float4*)(xpz + (long)(m0 + row) * 128 + (k0 - 128) + c4 * 4);
                *(short4*)&As[row * 40 + c4 * 4] =
                    make_short4(f2bf(v.x), f2bf(v.y), f2bf(v.z), f2bf(v.w));
            }
        }
        __syncthreads();
        s16x8 af[2], bf[4];
#pragma unroll
        for (int t = 0; t < 2; ++t) {
            int ar = wrow * 32 + t * 16 + lane16;
            af[t] = useXp ? *(const s16x8*)&As[ar * 40 + quad * 8]
                          : *(const s16x8*)&Tl[ar][k0 + quad * 8];
        }
#pragma unroll
        for (int j = 0; j < 4; ++j)
            bf[j] = *(const s16x8*)&Bs[(wcol * 64 + j * 16 + lane16) * 40 + quad * 8];
#pragma unroll
        for (int t = 0; t < 2; ++t)
#pragma unroll
            for (int j = 0; j < 4; ++j)
                acc2[t][j] = __builtin_amdgcn_mfma_f32_16x16x32_bf16(af[t], bf[j], acc2[t][j], 0, 0, 0);
        __syncthreads();
    }

    if (!COLSUM) {
        float* Of = (float*)Outv;
        short* Ob = (short*)Outv;
#pragma unroll
        for (int t = 0; t < 2; ++t) {
#pragma unroll
            for (int j = 0; j < 4; ++j) {
                int gcol = wcol * 64 + j * 16 + lane16;
                float bv = brel[gcol];
#pragma unroll
                for (int r = 0; r < 4; ++r) {
                    int grow = m0 + wrow * 32 + t * 16 + quad * 4 + r;
                    float val = acc2[t][j][r] + bv;
                    if (RELU) val = fmaxf(val, 0.f);
                    long oi = ((long)z * KADJ + grow) * 128 + gcol;
                    if (OBF16) Ob[oi] = f2bf(val);
                    else       Of[oi] = val;
                }
            }
        }
    } else {
#pragma unroll
        for (int j = 0; j < 4; ++j) {
            int gcol = wcol * 64 + j * 16 + lane16;
            float bv = brel[gcol];
            float p = 0.f;
#pragma unroll
            for (int t = 0; t < 2; ++t)
#pragma unroll
                for (int r = 0; r < 4; ++r) {
                    float val = acc2[t][j][r] + bv;
                    if (RELU) val = fmaxf(val, 0.f);
                    p += val;
                }
            atomicAdd(&cs[gcol], p);
        }
        __syncthreads();
        float* gsum = (float*)Outv;
        for (int i = tid; i < 128; i += 256)
            atomicAdd(&gsum[(long)z * 128 + i], cs[i]);
    }
}

// ---------------------------------------------------------------------------
// FUSED MLP + row-softmax: Out = softmax_row(A @ W + b), A bf16 [M,128],
// W f32 [128,NC], Out bf16 [M,NC]. TILE_M=64 (4 waves x 16 rows).
// ---------------------------------------------------------------------------
template <int NC>
__global__ __launch_bounds__(256) void mlp_softmax_kernel(const short* __restrict__ A,
                                                          const float* __restrict__ W,
                                                          const float* __restrict__ bias,
                                                          short* __restrict__ Out) {
    __shared__ __align__(16) short As[64 * 40];
    __shared__ __align__(16) short Ws[NC * 40];
    const int tid = threadIdx.x;
    const int lane16 = tid & 15;
    const int quad = (tid & 63) >> 4;
    const int wv = tid >> 6;
    const int m0 = blockIdx.x * 64;
    constexpr int NT = NC / 16;

    f32x4 acc[NT] = {};

    for (int k0 = 0; k0 < 128; k0 += 32) {
        {
            int row = tid >> 2, g = tid & 3;
            *(s16x8*)&As[row * 40 + g * 8] =
                *(const s16x8*)(A + (long)(m0 + row) * 128 + k0 + g * 8);
        }
#pragma unroll
        for (int p = 0; p < NC / 128; ++p) {
            int c4 = tid >> 3, g = tid & 7;
            int n0 = p * 128 + c4 * 4;
            short* d = &Ws[n0 * 40 + g * 4];
            const float* src = W + (long)(k0 + g * 4) * NC + n0;
            float4 r0 = *(const float4*)(src);
            float4 r1 = *(const float4*)(src + NC);
            float4 r2 = *(const float4*)(src + 2 * NC);
            float4 r3 = *(const float4*)(src + 3 * NC);
            *(short4*)(d + 0 * 40) = make_short4(f2bf(r0.x), f2bf(r1.x), f2bf(r2.x), f2bf(r3.x));
            *(short4*)(d + 1 * 40) = make_short4(f2bf(r0.y), f2bf(r1.y), f2bf(r2.y), f2bf(r3.y));
            *(short4*)(d + 2 * 40) = make_short4(f2bf(r0.z), f2bf(r1.z), f2bf(r2.z), f2bf(r3.z));
            *(short4*)(d + 3 * 40) = make_short4(f2bf(r0.w), f2bf(r1.w), f2bf(r2.w), f2bf(r3.w));
        }
        __syncthreads();

        s16x8 af = *(const s16x8*)&As[(wv * 16 + lane16) * 40 + quad * 8];
#pragma unroll
        for (int t = 0; t < NT; ++t) {
            s16x8 bf = *(const s16x8*)&Ws[(t * 16 + lane16) * 40 + quad * 8];
            acc[t] = __builtin_amdgcn_mfma_f32_16x16x32_bf16(af, bf, acc[t], 0, 0, 0);
        }
        __syncthreads();
    }

    float mx[4] = {-INFINITY, -INFINITY, -INFINITY, -INFINITY};
#pragma unroll
    for (int t = 0; t < NT; ++t) {
        float bv = bias[t * 16 + lane16];
#pragma unroll
        for (int r = 0; r < 4; ++r) {
            float x = bf2f(f2bf(acc[t][r] + bv));
            acc[t][r] = x;
            mx[r] = fmaxf(mx[r], x);
        }
    }
#pragma unroll
    for (int off = 8; off; off >>= 1)
#pragma unroll
        for (int r = 0; r < 4; ++r) mx[r] = fmaxf(mx[r], __shfl_xor(mx[r], off));
    float sm[4] = {0.f, 0.f, 0.f, 0.f};
#pragma unroll
    for (int t = 0; t < NT; ++t)
#pragma unroll
        for (int r = 0; r < 4; ++r) {
            float e = expf(acc[t][r] - mx[r]);
            acc[t][r] = e;
            sm[r] += e;
        }
#pragma unroll
    for (int off = 8; off; off >>= 1)
#pragma unroll
        for (int r = 0; r < 4; ++r) sm[r] += __shfl_xor(sm[r], off);
#pragma unroll
    for (int r = 0; r < 4; ++r) sm[r] = 1.f / sm[r];
#pragma unroll
    for (int t = 0; t < NT; ++t)
#pragma unroll
        for (int r = 0; r < 4; ++r)
            Out[(long)(m0 + wv * 16 + quad * 4 + r) * NC + t * 16 + lane16] =
                f2bf(acc[t][r] * sm[r]);
}

// ---------------------------------------------------------------------------
// BF16-input MFMA GEMM (TRANS_B — used for QK^T): C = scale*(A@B^T).
// Block remap: graph z runs on XCD z>>3 (matching attn_pv's consumer swizzle).
// ---------------------------------------------------------------------------
template <bool OBF16>
__global__ __launch_bounds__(256) void bgemm(const short* __restrict__ A,
                                             const short* __restrict__ B,
                                             void* __restrict__ Cv,
                                             float outscale,
                                             int M, int Nc, int K,
                                             int lda, int ldb, int ldc,
                                             long sA, long sB, long sC) {
    __shared__ __align__(16) short As[128 * 40];
    __shared__ __align__(16) short Bs[128 * 40];
    int L = blockIdx.x + (blockIdx.y << 2) + (blockIdx.z << 4);
    int xcd = L & 7, i = L >> 3;
    const int z = xcd * 8 + (i >> 4);
    const int m0 = ((i >> 2) & 3) * 128, n0 = (i & 3) * 128;
    A += (long)z * sA;
    B += (long)z * sB;
    float* C = (float*)Cv + (OBF16 ? 0 : (long)z * sC);
    short* Cs = (short*)Cv + (OBF16 ? (long)z * sC : 0);
    const int tid = threadIdx.x;
    const int lane16 = tid & 15;
    const int quad = (tid & 63) >> 4;
    const int wrow = (tid >> 6) >> 1, wcol = (tid >> 6) & 1;

    f32x4 acc[4][4] = {};

    for (int k0 = 0; k0 < K; k0 += 32) {
#pragma unroll
        for (int p = 0; p < 2; ++p) {
            int u = tid + p * 256;
            int row = u >> 2, g = u & 3;
            *(s16x8*)&As[row * 40 + g * 8] =
                *(const s16x8*)(A + (long)(m0 + row) * lda + k0 + g * 8);
        }
#pragma unroll
        for (int p = 0; p < 2; ++p) {
            int u = tid + p * 256;
            int row = u >> 2, g = u & 3;
            *(s16x8*)&Bs[row * 40 + g * 8] =
                *(const s16x8*)(B + (long)(n0 + row) * ldb + k0 + g * 8);
        }
        __syncthreads();

        s16x8 af[4], bf[4];
#pragma unroll
        for (int t = 0; t < 4; ++t) {
            af[t] = *(const s16x8*)&As[(wrow * 64 + t * 16 + lane16) * 40 + quad * 8];
            bf[t] = *(const s16x8*)&Bs[(wcol * 64 + t * 16 + lane16) * 40 + quad * 8];
        }
#pragma unroll
        for (int i2 = 0; i2 < 4; ++i2)
#pragma unroll
            for (int j = 0; j < 4; ++j)
                acc[i2][j] = __builtin_amdgcn_mfma_f32_16x16x32_bf16(af[i2], bf[j], acc[i2][j], 0, 0, 0);
        __syncthreads();
    }

#pragma unroll
    for (int i2 = 0; i2 < 4; ++i2) {
        int gm = m0 + wrow * 64 + i2 * 16 + quad * 4;
#pragma unroll
        for (int j = 0; j < 4; ++j) {
            int gn = n0 + wcol * 64 + j * 16 + lane16;
#pragma unroll
            for (int r = 0; r < 4; ++r) {
                float val = acc[i2][j][r] * outscale;
                if (OBF16) Cs[(long)(gm + r) * ldc + gn] = f2bf(val);
                else       C[(long)(gm + r) * ldc + gn] = val;
            }
        }
    }
}

// ---------------------------------------------------------------------------
// FUSED edge-softmax + PV gather. 16 lanes/dst node, XCD-swizzled blocks.
// S-row staged in LDS (round-3 structure — local optimum).
// ---------------------------------------------------------------------------
__global__ __launch_bounds__(256) void attn_pv_kernel(const short* __restrict__ S,
                                                      const int* __restrict__ ei,
                                                      const float* __restrict__ eattr,
                                                      const float* __restrict__ We,
                                                      const int* __restrict__ rp_dst,
                                                      const int* __restrict__ deg_dst,
                                                      const int* __restrict__ eid_dst,
                                                      const short* __restrict__ qkvs,
                                                      float* __restrict__ alpha,
                                                      short* __restrict__ h) {
    __shared__ float sWe[EDIM_ * 128];
    __shared__ __align__(16) short sS[16][528];   // 1KB S-row per group (+pad)
    int g = threadIdx.x >> 4;
    int lane = threadIdx.x & 15;
    int gbase = (threadIdx.x & 63) & ~15;
    int b = blockIdx.x;
    int xcd = b & 7, idx = b >> 3;
    int nb = (xcd * 8 + (idx >> 5)) * 32 + (idx & 31);
    int node = nb * 16 + g;

    {
        const short* Srow = S + (long)node * 512;
        short* Sl = sS[g];
#pragma unroll
        for (int j = 0; j < 4; ++j)
            *(s16x8*)&Sl[j * 128 + lane * 8] = *(const s16x8*)(Srow + j * 128 + lane * 8);
    }
    for (int i = threadIdx.x; i < EDIM_ * 128; i += 256) sWe[i] = We[i];
    __syncthreads();
    const short* Sl = sS[g];

    float qw[EDIM_];
    {
        s16x8 qv = *(const s16x8*)(qkvs + (long)node * 512 + lane * 8);
        float qf[8];
#pragma unroll
        for (int j = 0; j < 8; ++j) qf[j] = bf2f(qv[j]);
#pragma unroll
        for (int d = 0; d < EDIM_; ++d) {
            float p = 0.f;
#pragma unroll
            for (int j = 0; j < 8; ++j) p += qf[j] * sWe[d * 128 + lane * 8 + j];
            qw[d] = p;
        }
#pragma unroll
        for (int off = 8; off; off >>= 1)
#pragma unroll
            for (int d = 0; d < EDIM_; ++d) qw[d] += __shfl_xor(qw[d], off);
#pragma unroll
        for (int d = 0; d < EDIM_; ++d) qw[d] *= 0.08838834764831845f;
    }

    int start = rp_dst[node], cnt = deg_dst[node];
    int nch = (cnt + 15) >> 4;

    float lsum = 0.f, a5[EDIM_] = {};
    int   src_c[4] = {0, 0, 0, 0};
    float a_c[4]   = {0.f, 0.f, 0.f, 0.f};
    for (int c = 0; c < nch; ++c) {
        int t = c * 16 + lane;
        int src = 0; float wv = 0.f;
        if (t < cnt) {
            int e = eid_dst[start + t];
            src = ei[e];
            float lg = bf2f(Sl[src & 511]);
            float ea[EDIM_];
#pragma unroll
            for (int d = 0; d < EDIM_; ++d) { ea[d] = eattr[e * EDIM_ + d]; lg += ea[d] * qw[d]; }
            wv = expf(lg);
            lsum += wv;
#pragma unroll
            for (int d = 0; d < EDIM_; ++d) a5[d] += wv * ea[d];
        }
        if (c < 4) { src_c[c] = src; a_c[c] = wv; }
        else if (t < cnt) alpha[start + t] = wv;
    }
#pragma unroll
    for (int off = 8; off; off >>= 1) {
        lsum += __shfl_xor(lsum, off);
#pragma unroll
        for (int d = 0; d < EDIM_; ++d) a5[d] += __shfl_xor(a5[d], off);
    }
    float inv = (lsum > 0.f) ? 1.f / lsum : 0.f;
    float e5[EDIM_];
#pragma unroll
    for (int d = 0; d < EDIM_; ++d) e5[d] = a5[d] * inv;

    float acc[8] = {};
    for (int c = 0; c < nch; ++c) {
        int src; float a;
        if (c < 4) { src = src_c[c]; a = a_c[c]; }
        else {
            int t = c * 16 + lane;
            if (t < cnt) {
                int e = eid_dst[start + t];
                src = ei[e];
                a = alpha[start + t];
            } else { src = 0; a = 0.f; }
        }
        int m = min(16, cnt - c * 16);
        if (m == 16) {
#pragma unroll
            for (int j = 0; j < 16; ++j) {
                int   sj = __shfl(src, gbase + j);
                float aj = __shfl(a,   gbase + j);
                s16x8 v = *(const s16x8*)(qkvs + (long)sj * 512 + 256 + lane * 8);
#pragma unroll
                for (int k = 0; k < 8; ++k) acc[k] += aj * bf2f(v[k]);
            }
        } else {
            for (int j = 0; j < m; ++j) {
                int   sj = __shfl(src, gbase + j);
                float aj = __shfl(a,   gbase + j);
                s16x8 v = *(const s16x8*)(qkvs + (long)sj * 512 + 256 + lane * 8);
#pragma unroll
                for (int k = 0; k < 8; ++k) acc[k] += aj * bf2f(v[k]);
            }
        }
    }

    s16x8 sk = *(const s16x8*)(qkvs + (long)node * 512 + 384 + lane * 8);
    s16x8 o;
#pragma unroll
    for (int j = 0; j < 8; ++j) {
        float ec = 0.f;
#pragma unroll
        for (int d = 0; d < EDIM_; ++d) ec += e5[d] * sWe[d * 128 + lane * 8 + j];
        float val = acc[j] * inv + ec + bf2f(sk[j]);
        o[j] = f2bf(fmaxf(val, 0.f));
    }
    *(s16x8*)(h + (long)node * 128 + lane * 8) = o;
}

// ---------------------------------------------------------------------------
// T1 = A @ s1b computed SPARSELY over edges (src-CSR, XCD-swizzled)
// ---------------------------------------------------------------------------
__global__ __launch_bounds__(256) void t1_gather_kernel(const int* __restrict__ ei,
                                                        const int* __restrict__ rp_src,
                                                        const int* __restrict__ deg_src,
                                                        const int* __restrict__ eid_src,
                                                        const short* __restrict__ s1b,
                                                        short* __restrict__ T1s) {
    int g = threadIdx.x >> 4;
    int lane = threadIdx.x & 15;
    int gbase = (threadIdx.x & 63) & ~15;
    int b = blockIdx.x;
    int xcd = b & 7, idx = b >> 3;
    int nb = (xcd * 8 + (idx >> 5)) * 32 + (idx & 31);
    int node = nb * 16 + g;

    int start = rp_src[node], cnt = deg_src[node];
    int nch = (cnt + 15) >> 4;
    float acc[16] = {};
    for (int c = 0; c < nch; ++c) {
        int t = c * 16 + lane;
        int dst = 0;
        if (t < cnt) {
            int e = eid_src[start + t];
            dst = ei[EDGES + e];
        }
        int m = min(16, cnt - c * 16);
        if (m == 16) {
#pragma unroll
            for (int j = 0; j < 16; ++j) {
                int dj = __shfl(dst, gbase + j);
                const s16x8* p = (const s16x8*)(s1b + (long)dj * 256 + lane * 16);
                s16x8 v0 = p[0], v1 = p[1];
#pragma unroll
                for (int k = 0; k < 8; ++k) { acc[k] += bf2f(v0[k]); acc[8 + k] += bf2f(v1[k]); }
            }
        } else {
            for (int j = 0; j < m; ++j) {
                int dj = __shfl(dst, gbase + j);
                const s16x8* p = (const s16x8*)(s1b + (long)dj * 256 + lane * 16);
                s16x8 v0 = p[0], v1 = p[1];
#pragma unroll
                for (int k = 0; k < 8; ++k) { acc[k] += bf2f(v0[k]); acc[8 + k] += bf2f(v1[k]); }
            }
        }
    }
    s16x8 o0, o1;
#pragma unroll
    for (int k = 0; k < 8; ++k) { o0[k] = f2bf(acc[k]); o1[k] = f2bf(acc[8 + k]); }
    short* o = T1s + (long)node * 256 + lane * 16;
    *(s16x8*)(o)     = o0;
    *(s16x8*)(o + 8) = o1;
}

// ---------------------------------------------------------------------------
// Readout — g = gsum/128 (column sums accumulated by fused_gc3 COLSUM)
// ---------------------------------------------------------------------------
__global__ __launch_bounds__(128) void readout_kernel(const float* __restrict__ gsum,
                                                      const float* __restrict__ W_lin1,
                                                      const float* __restrict__ b_lin1,
                                                      const float* __restrict__ W_ro,
                                                      const float* __restrict__ b_ro,
                                                      float* __restrict__ out) {
    int b = blockIdx.x, t = threadIdx.x;
    __shared__ float g[128], g2[128], wred[2];
    g[t] = gsum[(long)b * 128 + t] * (1.f / (float)K2C);
    __syncthreads();
    float u = b_lin1[t];
    for (int k = 0; k < 128; ++k) u += g[k] * W_lin1[k * 128 + t];
    g2[t] = fmaxf(u, 0.f);
    __syncthreads();
    float p = g2[t] * W_ro[t];
#pragma unroll
    for (int off = 32; off; off >>= 1) p += __shfl_xor(p, off);
    if ((t & 63) == 0) wred[t >> 6] = p;
    __syncthreads();
    if (t == 0) {
        float tot = wred[0] + wred[1] + b_ro[0];
        out[b] = 1.f / (1.f + expf(-tot));
    }
}

// ---------------------------------------------------------------------------
extern "C" void kernel_launch(void* const* d_in, const int* in_sizes, int n_in,
                              void* d_out, int out_size, void* d_ws, size_t ws_size,
                              hipStream_t stream) {
    const float* x      = (const float*)d_in[0];
    const int*   ei     = (const int*)d_in[1];
    const float* eattr  = (const float*)d_in[2];
    const float* gamma  = (const float*)d_in[4];
    const float* beta   = (const float*)d_in[5];
    const float* Wq     = (const float*)d_in[6];
    const float* bq     = (const float*)d_in[7];
    const float* Wk     = (const float*)d_in[8];
    const float* bk     = (const float*)d_in[9];
    const float* Wv     = (const float*)d_in[10];
    const float* bv     = (const float*)d_in[11];
    const float* We     = (const float*)d_in[12];
    const float* Wskip  = (const float*)d_in[13];
    const float* bskip  = (const float*)d_in[14];
    const float* W_mlp1 = (const float*)d_in[15];
    const float* b_mlp1 = (const float*)d_in[16];
    const float* W2_rel = (const float*)d_in[17];
    const float* b2_rel = (const float*)d_in[18];
    const float* W2_root= (const float*)d_in[19];
    const float* W_mlp2 = (const float*)d_in[20];
    const float* b_mlp2 = (const float*)d_in[21];
    const float* W3_rel = (const float*)d_in[22];
    const float* b3_rel = (const float*)d_in[23];
    const float* W3_root= (const float*)d_in[24];
    const float* W_lin1 = (const float*)d_in[25];
    const float* b_lin1 = (const float*)d_in[26];
    const float* W_ro   = (const float*)d_in[27];
    const float* b_ro   = (const float*)d_in[28];
    float* out = (float*)d_out;

    char* w = (char*)d_ws;
    const size_t MB = 1ull << 20;
    // Workspace, lifetime-aliased (round-9 layout).
    short* qkvs = (short*)(w + 0);          // [NTOT,512] bf16 32MB (dead after step 6)
    short* S    = (short*)(w + 32 * MB);    // [NTOT,512] bf16 32MB (steps 5-6)
    short* T1s  = (short*)(w + 48 * MB);    // [NTOT,256] bf16 16MB (steps 8-9, over dead S hi)
    short* s1b  = (short*)(w + 64 * MB);    // [NTOT,256] bf16 16MB
    short* xd2  = (short*)(w + 56 * MB);    // [B,256,128] bf16 4MB
    short* s2b  = (short*)(w + 72 * MB);    // [B,256,128] bf16 4MB
    float* t2   = (float*)(w + 64 * MB);    // [B,256,128] fp32 8MB
    float* adj2 = (float*)(w + 0);          // [B,128,128] 4MB (raw)
    float* xp2  = (float*)(w + 4 * MB);     // [B,128,128] 4MB
    float* adj1 = (float*)(w + 80 * MB);    // [B,256,256] 16MB (raw)
    float* xp1  = (float*)(w + 96 * MB);    // [B,256,128] 8MB
    float* alpha= (float*)(w + 97 * MB);    // [EDGES] fp32 2MB (overflow spill; dead
                                            //  after attn_pv, before xp1 written)
    short* h    = (short*)(w + 112 * MB);   // [NTOT,128] bf16 8MB (steps 6-pool1)
    char* misc  = w + 104 * MB;
    float* W4     = (float*)(misc + 0x00000);
    float* bias4  = (float*)(misc + 0x40000);
    float* scale  = (float*)(misc + 0x41400);
    float* shift  = (float*)(misc + 0x41600);
    float* rowsum1= (float*)(misc + 0x42000);   // [B,256] fp32 64KB (zeroed)
    float* rowsum2= (float*)(misc + 0x52000);   // [B,128] fp32 32KB (zeroed)
    int* deg_src  = (int*)(misc + 0x60000);
    int* deg_dst  = (int*)(misc + 0x80000);
    int* rp_src   = (int*)(misc + 0xA0000);
    int* rp_dst   = (int*)(misc + 0xC0000);
    int* eid_src  = (int*)(misc + 0x120000);
    int* eid_dst  = (int*)(misc + 0x320000);
    float* psum   = (float*)(misc + 0x520000);
    float* psq    = (float*)(misc + 0x540000);
    float* gsum   = (float*)(misc + 0x560000);  // [B,128] fp32 32KB (zeroed in fin)

    // Zero rowsum1 + rowsum2 only (deg/rp/eid written directly by CSR build).
    hipMemsetAsync(misc + 0x42000, 0, 0x18000, stream);

    // 1. MERGED: BN stats + weight pack
    prep_kernel<<<512, 256, 0, stream>>>(x, psum, psq,
                                         Wq, Wk, Wv, Wskip, bq, bk, bv, bskip,
                                         W4, bias4);

    // 2. BN finalize + gsum zero
    fin_kernel<<<1, 1024, 0, stream>>>(psum, psq, gamma, beta, scale, shift, gsum);

    // 3. MERGED: qkvs GEMM ∥ per-graph LDS CSR build (no global atomics)
    qkvs_csr_kernel<<<1152, 256, 0, stream>>>(x, W4, bias4, qkvs, scale, shift,
                                              ei, rp_src, deg_src, eid_src,
                                              rp_dst, deg_dst, eid_dst);

    // 4. S(bf16) = (Q @ K^T) / sqrt(H) per graph (dense MFMA, XCD-aligned)
    bgemm<true><<<dim3(4, 4, BGRAPH), 256, 0, stream>>>(
        qkvs + 0, qkvs + 128, S, 0.08838834764831845f,
        NNODE, NNODE, 128, 512, 512, 512,
        (long)NNODE * 512, (long)NNODE * 512, (long)NNODE * NNODE);

    // 5. FUSED edge-softmax + PV gather -> h(bf16)
    attn_pv_kernel<<<NTOT / 16, 256, 0, stream>>>(
        S, ei, eattr, We, rp_dst, deg_dst, eid_dst, qkvs, alpha, h);

    // 6. s1b(bf16) = softmax_row(h @ W_mlp1 + b)
    mlp_softmax_kernel<K1C><<<NTOT / 64, 256, 0, stream>>>(h, W_mlp1, b_mlp1, s1b);

    // 7. T1(bf16) = A @ s1b via sparse edge gather (src-CSR)
    t1_gather_kernel<<<NTOT / 16, 256, 0, stream>>>(
        ei, rp_src, deg_src, eid_src, s1b, T1s);

    // 8. MERGED pool1: xp1 = s1b^T h ∥ adj1(raw) = s1b^T T1s (+ROWSUM)
    pool1_kernel<<<768, 256, 0, stream>>>(s1b, h, T1s, xp1, adj1, rowsum1);

    // 9. FUSED GraphConv2: xd2 = relu([adjN1@xp1 | xp1]@[W2_rel;W2_root]+b)
    fused_gc_kernel<K1C, true, true, false><<<dim3(4, BGRAPH), 256, 0, stream>>>(
        adj1, rowsum1, xp1, W2_rel, b2_rel, W2_root, xd2);

    // 10. s2b(bf16) = softmax_row(xd2 @ W_mlp2 + b)
    mlp_softmax_kernel<K2C><<<(BGRAPH * K1C) / 64, 256, 0, stream>>>(xd2, W_mlp2, b_mlp2, s2b);

    // 11. MERGED pool2: t2 = adjN1@s2b (ANORM) ∥ xp2 = s2b^T xd2
    pool2_kernel<<<768, 256, 0, stream>>>(adj1, rowsum1, s2b, xd2, t2, xp2);

    // 12. adj2(raw) = s2b^T t2 (+ROWSUM -> rowsum2)
    mgemm<64, true, false, false, true, false, false, false, false, false, true, false>
        <<<dim3(2, 2, BGRAPH), 256, 0, stream>>>(
        s2b, t2, nullptr, nullptr, 0, nullptr, adj2, nullptr, rowsum2,
        K2C, K2C, K1C, K2C, K2C, K2C,
        (long)K1C * K2C, (long)K1C * K2C, (long)K2C * K2C);

    // 13. FUSED GraphConv3 + COLSUM -> gsum (xd3 never materialized)
    fused_gc_kernel<K2C, false, false, true><<<dim3(2, BGRAPH), 256, 0, stream>>>(
        adj2, rowsum2, xp2, W3_rel, b3_rel, W3_root, gsum);

    // 14. Readout from gsum
    readout_kernel<<<BGRAPH, 128, 0, stream>>>(gsum, W_lin1, b_lin1, W_ro, b_ro, out);

    (void)in_sizes; (void)n_in; (void)out_size; (void)ws_size;
}